// Round 1
// baseline (669.752 us; speedup 1.0000x reference)
//
#include <hip/hip_runtime.h>
#include <stdint.h>

// Problem constants
#define TB 4
#define TT 8192
#define TD 1024
#define TS 32
#define TL 256
#define BT 32768   // TB*TT

typedef unsigned short u16;
typedef __bf16 bf16x8 __attribute__((ext_vector_type(8)));
typedef float f32x4 __attribute__((ext_vector_type(4)));

typedef uint32_t u32_g __attribute__((address_space(1)));
typedef uint32_t u32_l __attribute__((address_space(3)));

__device__ __forceinline__ u16 f2b(float f){
  union { float f; uint32_t u; } a; a.f = f;
  uint32_t r = a.u + 0x7FFFu + ((a.u >> 16) & 1u);
  return (u16)(r >> 16);
}
__device__ __forceinline__ float b2f(u16 u){
  union { uint32_t u; float f; } a; a.u = ((uint32_t)u) << 16;
  return a.f;
}
__device__ __forceinline__ void gll16(const void* g, void* l){
  __builtin_amdgcn_global_load_lds((const u32_g*)g, (u32_l*)l, 16, 0, 0);
}

// ---- convert f32 weight matrix -> bf16 (n4 = count/4) ----
__global__ void k_convw(const float* __restrict__ w, u16* __restrict__ o, int n4){
  int i = blockIdx.x*256 + threadIdx.x;
  if (i < n4){
    float4 v = ((const float4*)w)[i];
    ushort4 u; u.x=f2b(v.x); u.y=f2b(v.y); u.z=f2b(v.z); u.w=f2b(v.w);
    ((ushort4*)o)[i] = u;
  }
}

// ---- q[s,d] = sum_e ms[s,e] * Wq[d,e] ----
__global__ void k_prep_q(const float* __restrict__ ms, const float* __restrict__ Wq,
                         float* __restrict__ q){
  __shared__ float sm[TD];
  int s = blockIdx.y;
  int d = blockIdx.x*256 + threadIdx.x;
  for (int i = threadIdx.x; i < TD; i += 256) sm[i] = ms[s*TD + i];
  __syncthreads();
  const float* w = Wq + (size_t)d*TD;
  float a0=0.f, a1=0.f;
  for (int e=0; e<TD; e+=8){
    float4 w0 = *(const float4*)(w+e);
    float4 w1 = *(const float4*)(w+e+4);
    a0 += w0.x*sm[e]   + w0.y*sm[e+1] + w0.z*sm[e+2] + w0.w*sm[e+3];
    a1 += w1.x*sm[e+4] + w1.y*sm[e+5] + w1.z*sm[e+6] + w1.w*sm[e+7];
  }
  q[(size_t)s*TD + d] = a0 + a1;
}

// ---- qk[s,e] = scale * sum_d q[s,d] * Wk[d,e]  (pre-folded write-K projection) ----
__global__ void k_prep_qk(const float* __restrict__ q, const float* __restrict__ Wk,
                          float* __restrict__ qk){
  __shared__ float sq[TD];
  int s = blockIdx.x;
  int e = threadIdx.x*4;
  for (int i = threadIdx.x; i < TD; i += 256) sq[i] = q[s*TD + i];
  __syncthreads();
  float4 acc = {0,0,0,0};
  for (int d=0; d<TD; d+=4){
    float4 w0 = *(const float4*)(Wk + (size_t)d*TD + e);
    float4 w1 = *(const float4*)(Wk + (size_t)(d+1)*TD + e);
    float4 w2 = *(const float4*)(Wk + (size_t)(d+2)*TD + e);
    float4 w3 = *(const float4*)(Wk + (size_t)(d+3)*TD + e);
    acc.x += sq[d]*w0.x + sq[d+1]*w1.x + sq[d+2]*w2.x + sq[d+3]*w3.x;
    acc.y += sq[d]*w0.y + sq[d+1]*w1.y + sq[d+2]*w2.y + sq[d+3]*w3.y;
    acc.z += sq[d]*w0.z + sq[d+1]*w1.z + sq[d+2]*w2.z + sq[d+3]*w3.z;
    acc.w += sq[d]*w0.w + sq[d+1]*w1.w + sq[d+2]*w2.w + sq[d+3]*w3.w;
  }
  const float scale = 1.0f/32.0f;
  float4 o; o.x=acc.x*scale; o.y=acc.y*scale; o.z=acc.z*scale; o.w=acc.w*scale;
  *(float4*)(qk + (size_t)s*TD + e) = o;
}

// ---- single pass over x: convert to bf16 AND compute write logits wqk[bt] ----
__global__ void k_conv_dot(const float* __restrict__ x, const float* __restrict__ qk,
                           u16* __restrict__ xb, float* __restrict__ wqk){
  int lane = threadIdx.x & 63, wv = threadIdx.x >> 6;
  long bt0 = (long)blockIdx.x * 64;
  int sseg = (int)((bt0 & (TT-1)) >> 8);   // segment index (uniform across block: 64 | 256)
  float qv[16];
  #pragma unroll
  for (int i=0;i<4;i++){
    float4 t = *(const float4*)(qk + (size_t)sseg*TD + i*256 + lane*4);
    qv[i*4+0]=t.x; qv[i*4+1]=t.y; qv[i*4+2]=t.z; qv[i*4+3]=t.w;
  }
  for (int tok = wv; tok < 64; tok += 4){
    long bt = bt0 + tok;
    const float* xr = x + bt*TD;
    float dot = 0.f;
    #pragma unroll
    for (int i=0;i<4;i++){
      float4 t = *(const float4*)(xr + i*256 + lane*4);
      ushort4 u; u.x=f2b(t.x); u.y=f2b(t.y); u.z=f2b(t.z); u.w=f2b(t.w);
      *(ushort4*)(xb + bt*TD + i*256 + lane*4) = u;
      dot += t.x*qv[i*4] + t.y*qv[i*4+1] + t.z*qv[i*4+2] + t.w*qv[i*4+3];
    }
    #pragma unroll
    for (int o=32;o;o>>=1) dot += __shfl_xor(dot, o);
    if (lane == 0) wqk[bt] = dot;
  }
}

// ---- per (b,s): softmax over L=256 logits, xbar = sum_l w_l * x_l ----
__global__ void k_wattn(const float* __restrict__ wqk, const u16* __restrict__ xb,
                        float* __restrict__ xbar){
  __shared__ float sw[TL];
  __shared__ float red[8];
  int tid = threadIdx.x, lane = tid & 63, wv = tid >> 6;
  int b = blockIdx.x >> 5, s = blockIdx.x & 31;
  long base = (long)b*TT + (long)s*TL;
  float v = wqk[base + tid];
  float m = v;
  #pragma unroll
  for (int o=32;o;o>>=1) m = fmaxf(m, __shfl_xor(m, o));
  if (lane == 0) red[wv] = m;
  __syncthreads();
  m = fmaxf(fmaxf(red[0], red[1]), fmaxf(red[2], red[3]));
  float e = __expf(v - m);
  float sm = e;
  #pragma unroll
  for (int o=32;o;o>>=1) sm += __shfl_xor(sm, o);
  if (lane == 0) red[4+wv] = sm;
  __syncthreads();
  sm = red[4]+red[5]+red[6]+red[7];
  sw[tid] = e / sm;
  __syncthreads();
  int d0 = tid*4;
  float4 acc = {0,0,0,0};
  const u16* xp = xb + base*TD + d0;
  #pragma unroll 4
  for (int l=0; l<TL; ++l){
    float w = sw[l];
    ushort4 u = *(const ushort4*)(xp + (size_t)l*TD);
    acc.x += w*b2f(u.x); acc.y += w*b2f(u.y); acc.z += w*b2f(u.z); acc.w += w*b2f(u.w);
  }
  *(float4*)(xbar + ((size_t)b*TS + s)*TD + d0) = acc;
}

// ---- small matmul: C[128,1024] = A[128,1024] @ (modeT ? W^T : W), multi-format output ----
__global__ void k_mm(const float* __restrict__ A, const float* __restrict__ W,
                     int modeT, float scale,
                     float* __restrict__ Cf, float* __restrict__ Cf2,
                     u16* __restrict__ Cb, u16* __restrict__ CbT){
  __shared__ float sA[2][TD];
  int r0 = blockIdx.x*2;
  int n = blockIdx.y*256 + threadIdx.x;
  for (int i=threadIdx.x; i<2*TD; i+=256) sA[i>>10][i&1023] = A[(size_t)r0*TD + i];
  __syncthreads();
  float acc0=0.f, acc1=0.f;
  if (modeT){
    const float* w = W + (size_t)n*TD;
    for (int k=0;k<TD;k+=4){
      float4 wv = *(const float4*)(w+k);
      float4 a0 = *(const float4*)(&sA[0][k]);
      float4 a1 = *(const float4*)(&sA[1][k]);
      acc0 += wv.x*a0.x + wv.y*a0.y + wv.z*a0.z + wv.w*a0.w;
      acc1 += wv.x*a1.x + wv.y*a1.y + wv.z*a1.z + wv.w*a1.w;
    }
  } else {
    for (int k=0;k<TD;k+=4){
      float w0 = W[(size_t)k*TD + n],     w1 = W[(size_t)(k+1)*TD + n];
      float w2 = W[(size_t)(k+2)*TD + n], w3 = W[(size_t)(k+3)*TD + n];
      float4 a0 = *(const float4*)(&sA[0][k]);
      float4 a1 = *(const float4*)(&sA[1][k]);
      acc0 += w0*a0.x + w1*a0.y + w2*a0.z + w3*a0.w;
      acc1 += w0*a1.x + w1*a1.y + w2*a1.z + w3*a1.w;
    }
  }
  #pragma unroll
  for (int r=0;r<2;r++){
    float v = (r==0?acc0:acc1)*scale;
    int rr = r0 + r;
    size_t idx = (size_t)rr*TD + n;
    if (Cf)  Cf[idx]  = v;
    if (Cf2) Cf2[idx] = v;
    if (Cb)  Cb[idx]  = f2b(v);
    if (CbT){ int bb = rr >> 5, ss = rr & 31; CbT[((size_t)bb*TD + n)*TS + ss] = f2b(v); }
  }
}

// ---- big MFMA GEMM: C[32768,1024] = A @ W^T  (A bf16 [M][K], W bf16 [N][K]) ----
// m97 structure: 128x128 tile, BK=32, global_load_lds w16, double-buffered LDS
template<bool SIG>
__global__ __launch_bounds__(256) void k_gemm(const u16* __restrict__ A, const u16* __restrict__ Bw,
                                              const float* __restrict__ bias, void* __restrict__ Cp){
  __shared__ __align__(16) u16 sA[2][128*32];
  __shared__ __align__(16) u16 sB[2][128*32];
  int tid = threadIdx.x, lane = tid & 63, wv = tid >> 6;
  int bid = blockIdx.x;
  int wg = ((bid & 7) << 8) | (bid >> 3);   // XCD swizzle, 2048 % 8 == 0 -> bijective
  int nt = wg & 7, mt = wg >> 3;
  int m0 = mt*128, n0 = nt*128;
  int wr = wv >> 1, wc = wv & 1;
  int r15 = lane & 15, kg = lane >> 4;

  f32x4 z4 = {0.f,0.f,0.f,0.f};
  f32x4 acc[4][4];
  #pragma unroll
  for (int i=0;i<4;i++){
    #pragma unroll
    for (int j=0;j<4;j++) acc[i][j] = z4;
  }

  auto stage = [&](int buf, int k0){
    #pragma unroll
    for (int r=0;r<2;r++){
      int c = r*256 + tid;
      int row = c >> 2, kc = c & 3;
      gll16(A + (size_t)(m0 + row)*TD + k0 + kc*8, &sA[buf][(r*256 + wv*64)*8]);
    }
    #pragma unroll
    for (int r=0;r<2;r++){
      int c = r*256 + tid;
      int row = c >> 2, kc = c & 3;
      gll16(Bw + (size_t)(n0 + row)*TD + k0 + kc*8, &sB[buf][(r*256 + wv*64)*8]);
    }
  };

  stage(0, 0);
  __syncthreads();
  int cur = 0;
  for (int kk=0; kk<TD/32; ++kk){
    if (kk+1 < TD/32) stage(cur^1, (kk+1)*32);
    bf16x8 af[4], bfg[4];
    #pragma unroll
    for (int i=0;i<4;i++){
      af[i]  = *(const bf16x8*)&sA[cur][(wr*64 + i*16 + r15)*32 + kg*8];
      bfg[i] = *(const bf16x8*)&sB[cur][(wc*64 + i*16 + r15)*32 + kg*8];
    }
    #pragma unroll
    for (int i=0;i<4;i++){
      #pragma unroll
      for (int j=0;j<4;j++)
        acc[i][j] = __builtin_amdgcn_mfma_f32_16x16x32_bf16(af[i], bfg[j], acc[i][j], 0, 0, 0);
    }
    __syncthreads();
    cur ^= 1;
  }

  float bb[4];
  if (SIG && bias){
    #pragma unroll
    for (int j=0;j<4;j++) bb[j] = bias[n0 + wc*64 + j*16 + r15];
  } else { bb[0]=bb[1]=bb[2]=bb[3]=0.f; }
  #pragma unroll
  for (int i=0;i<4;i++){
    int rbase = m0 + wr*64 + i*16 + kg*4;
    #pragma unroll
    for (int j=0;j<4;j++){
      int c = n0 + wc*64 + j*16 + r15;
      #pragma unroll
      for (int q=0;q<4;q++){
        float v = acc[i][j][q] + bb[j];
        size_t idx = (size_t)(rbase + q)*TD + c;
        if (SIG){
          v = 1.f/(1.f + __expf(-v));
          ((u16*)Cp)[idx] = f2b(v);
        } else {
          ((float*)Cp)[idx] = v;
        }
      }
    }
  }
}

// ---- fused read attention: logits (MFMA) -> masked softmax -> PV (MFMA) -> y = x + g*read ----
// y overwrites gy in place.
__global__ __launch_bounds__(256) void k_read(const u16* __restrict__ xb, u16* __restrict__ gy,
                                              const u16* __restrict__ rkb, const u16* __restrict__ rvT){
  __shared__ __align__(16) u16 sP[64*32];
  __shared__ float sSum[64];
  int tid = threadIdx.x, lane = tid & 63, wv = tid >> 6;
  long bt0 = (long)blockIdx.x * 64;
  int b = (int)(bt0 >> 13);
  int smin = (int)((bt0 & (TT-1)) >> 8);
  int r15 = lane & 15, kg = lane >> 4;

  // QK: wave handles 16 tokens
  {
    long tw = bt0 + wv*16;
    const u16* ap  = xb  + (size_t)(tw + r15)*TD + kg*8;
    const u16* bp0 = rkb + ((size_t)(b*TS + r15))*TD + kg*8;
    const u16* bp1 = rkb + ((size_t)(b*TS + 16 + r15))*TD + kg*8;
    f32x4 p0 = {0,0,0,0}, p1 = {0,0,0,0};
    #pragma unroll 4
    for (int ks=0; ks<32; ++ks){
      bf16x8 a  = *(const bf16x8*)(ap  + ks*32);
      bf16x8 b0 = *(const bf16x8*)(bp0 + ks*32);
      bf16x8 b1 = *(const bf16x8*)(bp1 + ks*32);
      p0 = __builtin_amdgcn_mfma_f32_16x16x32_bf16(a, b0, p0, 0,0,0);
      p1 = __builtin_amdgcn_mfma_f32_16x16x32_bf16(a, b1, p1, 0,0,0);
    }
    bool msk0 = (r15 < smin), msk1 = (16 + r15 < smin);
    #pragma unroll
    for (int q=0;q<4;q++){
      float l0 = msk0 ? -1e30f : p0[q];
      float l1 = msk1 ? -1e30f : p1[q];
      float mx = fmaxf(l0, l1);
      #pragma unroll
      for (int o=1;o<16;o<<=1) mx = fmaxf(mx, __shfl_xor(mx, o));
      float e0 = msk0 ? 0.f : __expf(l0 - mx);
      float e1 = msk1 ? 0.f : __expf(l1 - mx);
      float smv = e0 + e1;
      #pragma unroll
      for (int o=1;o<16;o<<=1) smv += __shfl_xor(smv, o);
      int trow = wv*16 + 4*kg + q;
      sP[trow*32 + r15]      = f2b(e0);
      sP[trow*32 + 16 + r15] = f2b(e1);
      if (r15 == 0) sSum[trow] = smv;
    }
  }
  __syncthreads();

  // PV: wave handles d-slice [wv*256, wv*256+256)
  int dbase = wv*256 + r15;
  #pragma unroll
  for (int h=0; h<2; ++h){
    bf16x8 bfr[8];
    #pragma unroll
    for (int nf=0; nf<8; ++nf){
      int d = dbase + (h*8 + nf)*16;
      bfr[nf] = *(const bf16x8*)(rvT + ((size_t)b*TD + d)*TS + kg*8);
    }
    #pragma unroll
    for (int mi=0; mi<4; ++mi){
      bf16x8 af = *(const bf16x8*)(sP + (mi*16 + r15)*32 + kg*8);
      float rs[4];
      #pragma unroll
      for (int q=0;q<4;q++) rs[q] = 1.f / sSum[mi*16 + 4*kg + q];
      #pragma unroll
      for (int nf=0; nf<8; ++nf){
        f32x4 z = {0,0,0,0};
        f32x4 acc = __builtin_amdgcn_mfma_f32_16x16x32_bf16(af, bfr[nf], z, 0,0,0);
        int d = dbase + (h*8 + nf)*16;
        #pragma unroll
        for (int q=0;q<4;q++){
          size_t idx = (size_t)(bt0 + mi*16 + 4*kg + q)*TD + d;
          float xv = b2f(xb[idx]);
          float gv = b2f(gy[idx]);
          gy[idx] = f2b(xv + gv*acc[q]*rs[q]);
        }
      }
    }
  }
}

extern "C" void kernel_launch(void* const* d_in, const int* in_sizes, int n_in,
                              void* d_out, int out_size, void* d_ws, size_t ws_size,
                              hipStream_t stream){
  const float* x   = (const float*)d_in[0];
  const float* gw  = (const float*)d_in[1];
  const float* gb  = (const float*)d_in[2];
  const float* rqw = (const float*)d_in[3];
  const float* rkw = (const float*)d_in[4];
  const float* rvw = (const float*)d_in[5];
  const float* ow  = (const float*)d_in[6];
  const float* ms  = (const float*)d_in[7];
  const float* wqw = (const float*)d_in[8];
  const float* wkw = (const float*)d_in[9];
  const float* wvw = (const float*)d_in[10];
  float* out = (float*)d_out;
  float* mem_out = out + (size_t)BT*TD;

  // xb (bf16 copy of x, 64MB) lives in the front of d_out: dead before the
  // final GEMM writes out over it.
  u16* xb = (u16*)d_out;

  char* w = (char*)d_ws;
  u16*   gy    = (u16*)(w);                    // 64MB  (g = sigmoid(h), overwritten with y)
  float* wqkb  = (float*)(w + 67108864);       // 128KB
  float* qb    = (float*)(w + 67239936);       // 128KB
  float* qkb   = (float*)(w + 67371008);       // 128KB
  float* xbarb = (float*)(w + 67502080);       // 512KB
  float* memb  = (float*)(w + 68026368);       // 512KB
  float* rkbf  = (float*)(w + 68550656);       // 512KB
  u16*   rkb   = (u16*)(w + 69074944);         // 256KB
  u16*   rvT   = (u16*)(w + 69337088);         // 256KB
  u16*   gwb   = (u16*)(w + 69599232);         // 2MB
  u16*   owb   = (u16*)(w + 71696384);         // 2MB  -> total ~70.3MB

  k_convw<<<1024,256,0,stream>>>(gw, gwb, 262144);
  k_convw<<<1024,256,0,stream>>>(ow, owb, 262144);
  k_prep_q<<<dim3(4,32),256,0,stream>>>(ms, wqw, qb);
  k_prep_qk<<<32,256,0,stream>>>(qb, wkw, qkb);
  k_conv_dot<<<512,256,0,stream>>>(x, qkb, xb, wqkb);
  k_wattn<<<128,256,0,stream>>>(wqkb, xb, xbarb);
  // memory = xbar @ Wv^T   (also written to output slot 1)
  k_mm<<<dim3(64,4),256,0,stream>>>(xbarb, wvw, 1, 1.f, memb, mem_out, nullptr, nullptr);
  // rk = memory @ Wrk^T
  k_mm<<<dim3(64,4),256,0,stream>>>(memb, rkw, 1, 1.f, rkbf, nullptr, nullptr, nullptr);
  // rv = memory @ Wrv^T -> transposed bf16 [b][d][s]
  k_mm<<<dim3(64,4),256,0,stream>>>(memb, rvw, 1, 1.f, nullptr, nullptr, nullptr, rvT);
  // rk~ = scale * rk @ Wrq -> bf16 [b*s][d]
  k_mm<<<dim3(64,4),256,0,stream>>>(rkbf, rqw, 0, 1.f/32.f, nullptr, nullptr, rkb, nullptr);
  // g = sigmoid(x @ gate_w^T + gate_b)
  k_gemm<true><<<2048,256,0,stream>>>(xb, gwb, gb, gy);
  // y = x + g * read   (in place over gy)
  k_read<<<512,256,0,stream>>>(xb, gy, rkb, rvT);
  // out = y @ output_w^T
  k_gemm<false><<<2048,256,0,stream>>>(gy, owb, nullptr, d_out);
}

// Round 2
// 573.982 us; speedup vs baseline: 1.1669x; 1.1669x over previous
//
#include <hip/hip_runtime.h>
#include <stdint.h>

// Problem constants
#define TB 4
#define TT 8192
#define TD 1024
#define TS 32
#define TL 256
#define BT 32768   // TB*TT

typedef unsigned short u16;
typedef __bf16 bf16x8 __attribute__((ext_vector_type(8)));
typedef float f32x4 __attribute__((ext_vector_type(4)));

typedef uint32_t u32_g __attribute__((address_space(1)));
typedef uint32_t u32_l __attribute__((address_space(3)));

__device__ __forceinline__ u16 f2b(float f){
  union { float f; uint32_t u; } a; a.f = f;
  uint32_t r = a.u + 0x7FFFu + ((a.u >> 16) & 1u);
  return (u16)(r >> 16);
}
__device__ __forceinline__ float b2f(u16 u){
  union { uint32_t u; float f; } a; a.u = ((uint32_t)u) << 16;
  return a.f;
}
__device__ __forceinline__ void gll16(const void* g, void* l){
  __builtin_amdgcn_global_load_lds((const u32_g*)g, (u32_l*)l, 16, 0, 0);
}

// ---- convert both f32 weight matrices -> bf16 in one launch ----
__global__ void k_convw2(const float* __restrict__ a, const float* __restrict__ b,
                         u16* __restrict__ oa, u16* __restrict__ ob){
  int i = blockIdx.x*256 + threadIdx.x;   // 0 .. 524287
  const float* src; u16* dst; int j;
  if (i < 262144){ src = a; dst = oa; j = i; }
  else           { src = b; dst = ob; j = i - 262144; }
  float4 v = ((const float4*)src)[j];
  ushort4 u; u.x=f2b(v.x); u.y=f2b(v.y); u.z=f2b(v.z); u.w=f2b(v.w);
  ((ushort4*)dst)[j] = u;
}

// ---- q[s,d] = sum_e ms[s,e] * Wq[d,e] ----
__global__ void k_prep_q(const float* __restrict__ ms, const float* __restrict__ Wq,
                         float* __restrict__ q){
  __shared__ float sm[TD];
  int s = blockIdx.y;
  int d = blockIdx.x*256 + threadIdx.x;
  for (int i = threadIdx.x; i < TD; i += 256) sm[i] = ms[s*TD + i];
  __syncthreads();
  const float* w = Wq + (size_t)d*TD;
  float a0=0.f, a1=0.f;
  for (int e=0; e<TD; e+=8){
    float4 w0 = *(const float4*)(w+e);
    float4 w1 = *(const float4*)(w+e+4);
    a0 += w0.x*sm[e]   + w0.y*sm[e+1] + w0.z*sm[e+2] + w0.w*sm[e+3];
    a1 += w1.x*sm[e+4] + w1.y*sm[e+5] + w1.z*sm[e+6] + w1.w*sm[e+7];
  }
  q[(size_t)s*TD + d] = a0 + a1;
}

// ---- qk[s,e] = scale * sum_d q[s,d] * Wk[d,e]  -- grid (32 s, 4 e-chunks), d split 4-way ----
__global__ void k_prep_qk(const float* __restrict__ q, const float* __restrict__ Wk,
                          float* __restrict__ qk){
  __shared__ float sq[TD];
  __shared__ f32x4 part[4][64];
  int s = blockIdx.x;
  int tid = threadIdx.x;
  int ds = tid >> 6, e4 = tid & 63;
  int e = blockIdx.y*256 + e4*4;
  for (int i = tid; i < TD; i += 256) sq[i] = q[s*TD + i];
  __syncthreads();
  f32x4 acc = {0,0,0,0};
  int d0 = ds*256;
  #pragma unroll 4
  for (int d = d0; d < d0+256; ++d){
    float4 w = *(const float4*)(Wk + (size_t)d*TD + e);
    float sv = sq[d];
    acc[0] += sv*w.x; acc[1] += sv*w.y; acc[2] += sv*w.z; acc[3] += sv*w.w;
  }
  part[ds][e4] = acc;
  __syncthreads();
  if (ds == 0){
    f32x4 t = part[0][e4];
    f32x4 t1 = part[1][e4], t2 = part[2][e4], t3 = part[3][e4];
    const float scale = 1.0f/32.0f;
    float4 o;
    o.x = (t[0]+t1[0]+t2[0]+t3[0])*scale;
    o.y = (t[1]+t1[1]+t2[1]+t3[1])*scale;
    o.z = (t[2]+t1[2]+t2[2]+t3[2])*scale;
    o.w = (t[3]+t1[3]+t2[3]+t3[3])*scale;
    *(float4*)(qk + (size_t)s*TD + e) = o;
  }
}

// ---- single pass over x: convert to bf16 AND compute write logits wqk[bt] ----
__global__ void k_conv_dot(const float* __restrict__ x, const float* __restrict__ qk,
                           u16* __restrict__ xb, float* __restrict__ wqk){
  int lane = threadIdx.x & 63, wv = threadIdx.x >> 6;
  long bt0 = (long)blockIdx.x * 64;
  int sseg = (int)((bt0 & (TT-1)) >> 8);   // segment index (uniform across block)
  float qv[16];
  #pragma unroll
  for (int i=0;i<4;i++){
    float4 t = *(const float4*)(qk + (size_t)sseg*TD + i*256 + lane*4);
    qv[i*4+0]=t.x; qv[i*4+1]=t.y; qv[i*4+2]=t.z; qv[i*4+3]=t.w;
  }
  for (int tok = wv; tok < 64; tok += 4){
    long bt = bt0 + tok;
    const float* xr = x + bt*TD;
    float dot = 0.f;
    #pragma unroll
    for (int i=0;i<4;i++){
      float4 t = *(const float4*)(xr + i*256 + lane*4);
      ushort4 u; u.x=f2b(t.x); u.y=f2b(t.y); u.z=f2b(t.z); u.w=f2b(t.w);
      *(ushort4*)(xb + bt*TD + i*256 + lane*4) = u;
      dot += t.x*qv[i*4] + t.y*qv[i*4+1] + t.z*qv[i*4+2] + t.w*qv[i*4+3];
    }
    #pragma unroll
    for (int o=32;o;o>>=1) dot += __shfl_xor(dot, o);
    if (lane == 0) wqk[bt] = dot;
  }
}

// ---- per (b,s,dchunk): recompute softmax (cheap), accumulate xbar d-slice ----
__global__ void k_wattn(const float* __restrict__ wqk, const u16* __restrict__ xb,
                        float* __restrict__ xbar){
  __shared__ float sw[TL];
  __shared__ float red[8];
  int tid = threadIdx.x, lane = tid & 63, wv = tid >> 6;
  int b = blockIdx.x >> 5, s = blockIdx.x & 31;
  long base = (long)b*TT + (long)s*TL;
  float v = wqk[base + tid];
  float m = v;
  #pragma unroll
  for (int o=32;o;o>>=1) m = fmaxf(m, __shfl_xor(m, o));
  if (lane == 0) red[wv] = m;
  __syncthreads();
  m = fmaxf(fmaxf(red[0], red[1]), fmaxf(red[2], red[3]));
  float e = __expf(v - m);
  float sm = e;
  #pragma unroll
  for (int o=32;o;o>>=1) sm += __shfl_xor(sm, o);
  if (lane == 0) red[4+wv] = sm;
  __syncthreads();
  sm = red[4]+red[5]+red[6]+red[7];
  sw[tid] = e / sm;
  __syncthreads();
  int d = blockIdx.y*256 + tid;
  const u16* xp = xb + base*TD + d;
  float acc = 0.f;
  #pragma unroll 8
  for (int l=0; l<TL; ++l){
    acc += sw[l]*b2f(xp[(size_t)l*TD]);
  }
  xbar[((size_t)b*TS + s)*TD + d] = acc;
}

// ---- small matmul: C[128,1024] = A[128,1024] @ (modeT ? W^T : W), multi-format output ----
__global__ void k_mm(const float* __restrict__ A, const float* __restrict__ W,
                     int modeT, float scale,
                     float* __restrict__ Cf, float* __restrict__ Cf2,
                     u16* __restrict__ Cb, u16* __restrict__ CbT){
  __shared__ float sA[2][TD];
  int r0 = blockIdx.x*2;
  int n = blockIdx.y*256 + threadIdx.x;
  for (int i=threadIdx.x; i<2*TD; i+=256) sA[i>>10][i&1023] = A[(size_t)r0*TD + i];
  __syncthreads();
  float acc0=0.f, acc1=0.f;
  if (modeT){
    const float* w = W + (size_t)n*TD;
    for (int k=0;k<TD;k+=4){
      float4 wv = *(const float4*)(w+k);
      float4 a0 = *(const float4*)(&sA[0][k]);
      float4 a1 = *(const float4*)(&sA[1][k]);
      acc0 += wv.x*a0.x + wv.y*a0.y + wv.z*a0.z + wv.w*a0.w;
      acc1 += wv.x*a1.x + wv.y*a1.y + wv.z*a1.z + wv.w*a1.w;
    }
  } else {
    for (int k=0;k<TD;k+=4){
      float w0 = W[(size_t)k*TD + n],     w1 = W[(size_t)(k+1)*TD + n];
      float w2 = W[(size_t)(k+2)*TD + n], w3 = W[(size_t)(k+3)*TD + n];
      float4 a0 = *(const float4*)(&sA[0][k]);
      float4 a1 = *(const float4*)(&sA[1][k]);
      acc0 += w0*a0.x + w1*a0.y + w2*a0.z + w3*a0.w;
      acc1 += w0*a1.x + w1*a1.y + w2*a1.z + w3*a1.w;
    }
  }
  #pragma unroll
  for (int r=0;r<2;r++){
    float v = (r==0?acc0:acc1)*scale;
    int rr = r0 + r;
    size_t idx = (size_t)rr*TD + n;
    if (Cf)  Cf[idx]  = v;
    if (Cf2) Cf2[idx] = v;
    if (Cb)  Cb[idx]  = f2b(v);
    if (CbT){ int bb = rr >> 5, ss = rr & 31; CbT[((size_t)bb*TD + n)*TS + ss] = f2b(v); }
  }
}

// ---- merged rk/rv matmuls (same A=memory, modeT): z=0 -> rkbf f32, z=1 -> rvT bf16 transposed ----
__global__ void k_mm23(const float* __restrict__ A, const float* __restrict__ W0,
                       const float* __restrict__ W1,
                       float* __restrict__ rkbf, u16* __restrict__ rvT){
  __shared__ float sA[2][TD];
  const float* W = blockIdx.z ? W1 : W0;
  int r0 = blockIdx.x*2;
  int n = blockIdx.y*256 + threadIdx.x;
  for (int i=threadIdx.x; i<2*TD; i+=256) sA[i>>10][i&1023] = A[(size_t)r0*TD + i];
  __syncthreads();
  float acc0=0.f, acc1=0.f;
  const float* w = W + (size_t)n*TD;
  for (int k=0;k<TD;k+=4){
    float4 wv = *(const float4*)(w+k);
    float4 a0 = *(const float4*)(&sA[0][k]);
    float4 a1 = *(const float4*)(&sA[1][k]);
    acc0 += wv.x*a0.x + wv.y*a0.y + wv.z*a0.z + wv.w*a0.w;
    acc1 += wv.x*a1.x + wv.y*a1.y + wv.z*a1.z + wv.w*a1.w;
  }
  #pragma unroll
  for (int r=0;r<2;r++){
    float v = (r==0?acc0:acc1);
    int rr = r0 + r;
    if (blockIdx.z == 0){
      rkbf[(size_t)rr*TD + n] = v;
    } else {
      int bb = rr >> 5, ss = rr & 31;
      rvT[((size_t)bb*TD + n)*TS + ss] = f2b(v);
    }
  }
}

// ---- big MFMA GEMM: C[32768,1024] = A @ W^T  (A bf16 [M][K], W bf16 [N][K]) ----
// m97 structure; mfma(B,A) operand order -> lane holds 4 consecutive n -> vector stores
template<bool SIG>
__global__ __launch_bounds__(256) void k_gemm(const u16* __restrict__ A, const u16* __restrict__ Bw,
                                              const float* __restrict__ bias, void* __restrict__ Cp){
  __shared__ __align__(16) u16 sA[2][128*32];
  __shared__ __align__(16) u16 sB[2][128*32];
  int tid = threadIdx.x, lane = tid & 63, wv = tid >> 6;
  int bid = blockIdx.x;
  int wg = ((bid & 7) << 8) | (bid >> 3);   // XCD swizzle, 2048 % 8 == 0 -> bijective
  int nt = wg & 7, mt = wg >> 3;
  int m0 = mt*128, n0 = nt*128;
  int wr = wv >> 1, wc = wv & 1;
  int r15 = lane & 15, kg = lane >> 4;

  f32x4 z4 = {0.f,0.f,0.f,0.f};
  f32x4 acc[4][4];
  #pragma unroll
  for (int i=0;i<4;i++){
    #pragma unroll
    for (int j=0;j<4;j++) acc[i][j] = z4;
  }

  auto stage = [&](int buf, int k0){
    #pragma unroll
    for (int r=0;r<2;r++){
      int c = r*256 + tid;
      int row = c >> 2, kc = c & 3;
      gll16(A + (size_t)(m0 + row)*TD + k0 + kc*8, &sA[buf][(r*256 + wv*64)*8]);
    }
    #pragma unroll
    for (int r=0;r<2;r++){
      int c = r*256 + tid;
      int row = c >> 2, kc = c & 3;
      gll16(Bw + (size_t)(n0 + row)*TD + k0 + kc*8, &sB[buf][(r*256 + wv*64)*8]);
    }
  };

  stage(0, 0);
  __syncthreads();
  int cur = 0;
  for (int kk=0; kk<TD/32; ++kk){
    if (kk+1 < TD/32) stage(cur^1, (kk+1)*32);
    bf16x8 af[4], bfg[4];
    #pragma unroll
    for (int i=0;i<4;i++){
      af[i]  = *(const bf16x8*)&sA[cur][(wr*64 + i*16 + r15)*32 + kg*8];
      bfg[i] = *(const bf16x8*)&sB[cur][(wc*64 + i*16 + r15)*32 + kg*8];
    }
    #pragma unroll
    for (int i=0;i<4;i++){
      #pragma unroll
      for (int j=0;j<4;j++)
        acc[i][j] = __builtin_amdgcn_mfma_f32_16x16x32_bf16(bfg[j], af[i], acc[i][j], 0, 0, 0);
    }
    __syncthreads();
    cur ^= 1;
  }

  // C-frag (transposed mapping): row = n-offset = kg*4+q, col = m-offset = r15
  float4 b4[4];
  if (SIG){
    #pragma unroll
    for (int j=0;j<4;j++) b4[j] = *(const float4*)(bias + n0 + wc*64 + j*16 + kg*4);
  }
  #pragma unroll
  for (int i=0;i<4;i++){
    size_t m = (size_t)(m0 + wr*64 + i*16 + r15);
    #pragma unroll
    for (int j=0;j<4;j++){
      int nb = n0 + wc*64 + j*16 + kg*4;
      f32x4 v = acc[i][j];
      if (SIG){
        ushort4 u;
        u.x = f2b(1.f/(1.f + __expf(-(v[0] + b4[j].x))));
        u.y = f2b(1.f/(1.f + __expf(-(v[1] + b4[j].y))));
        u.z = f2b(1.f/(1.f + __expf(-(v[2] + b4[j].z))));
        u.w = f2b(1.f/(1.f + __expf(-(v[3] + b4[j].w))));
        *(ushort4*)((u16*)Cp + m*TD + nb) = u;
      } else {
        float4 o; o.x=v[0]; o.y=v[1]; o.z=v[2]; o.w=v[3];
        *(float4*)((float*)Cp + m*TD + nb) = o;
      }
    }
  }
}

// ---- fused read attention: logits (MFMA) -> masked softmax -> PV (MFMA) -> y = x + g*read ----
// PV uses mfma(V,P) so each lane holds 4 consecutive d -> ushort4 epilogue. y overwrites gy.
__global__ __launch_bounds__(256) void k_read(const u16* __restrict__ xb, u16* __restrict__ gy,
                                              const u16* __restrict__ rkb, const u16* __restrict__ rvT){
  __shared__ __align__(16) u16 sP[64*32];
  __shared__ float sSum[64];
  int tid = threadIdx.x, lane = tid & 63, wv = tid >> 6;
  long bt0 = (long)blockIdx.x * 64;
  int b = (int)(bt0 >> 13);
  int smin = (int)((bt0 & (TT-1)) >> 8);
  int r15 = lane & 15, kg = lane >> 4;

  // QK: wave handles 16 tokens; mfma(x-tokens, rk-slots): row=token(4kg+q), col=slot(r15)
  {
    long tw = bt0 + wv*16;
    const u16* ap  = xb  + (size_t)(tw + r15)*TD + kg*8;
    const u16* bp0 = rkb + ((size_t)(b*TS + r15))*TD + kg*8;
    const u16* bp1 = rkb + ((size_t)(b*TS + 16 + r15))*TD + kg*8;
    f32x4 p0 = {0,0,0,0}, p1 = {0,0,0,0};
    #pragma unroll 4
    for (int ks=0; ks<32; ++ks){
      bf16x8 a  = *(const bf16x8*)(ap  + ks*32);
      bf16x8 b0 = *(const bf16x8*)(bp0 + ks*32);
      bf16x8 b1 = *(const bf16x8*)(bp1 + ks*32);
      p0 = __builtin_amdgcn_mfma_f32_16x16x32_bf16(a, b0, p0, 0,0,0);
      p1 = __builtin_amdgcn_mfma_f32_16x16x32_bf16(a, b1, p1, 0,0,0);
    }
    bool msk0 = (r15 < smin), msk1 = (16 + r15 < smin);
    #pragma unroll
    for (int q=0;q<4;q++){
      float l0 = msk0 ? -1e30f : p0[q];
      float l1 = msk1 ? -1e30f : p1[q];
      float mx = fmaxf(l0, l1);
      #pragma unroll
      for (int o=1;o<16;o<<=1) mx = fmaxf(mx, __shfl_xor(mx, o));
      float e0 = msk0 ? 0.f : __expf(l0 - mx);
      float e1 = msk1 ? 0.f : __expf(l1 - mx);
      float smv = e0 + e1;
      #pragma unroll
      for (int o=1;o<16;o<<=1) smv += __shfl_xor(smv, o);
      int trow = wv*16 + 4*kg + q;
      sP[trow*32 + r15]      = f2b(e0);
      sP[trow*32 + 16 + r15] = f2b(e1);
      if (r15 == 0) sSum[trow] = smv;
    }
  }
  __syncthreads();

  // PV: wave handles d-slice [wv*256, wv*256+256); mfma(V,P): row=d(kg*4+q), col=token(r15)
  int dbase = wv*256 + r15;
  #pragma unroll
  for (int h=0; h<2; ++h){
    bf16x8 bfr[8];
    #pragma unroll
    for (int nf=0; nf<8; ++nf){
      int d = dbase + (h*8 + nf)*16;
      bfr[nf] = *(const bf16x8*)(rvT + ((size_t)b*TD + d)*TS + kg*8);
    }
    #pragma unroll
    for (int mi=0; mi<4; ++mi){
      bf16x8 af = *(const bf16x8*)(sP + (mi*16 + r15)*32 + kg*8);
      float rsv = 1.f / sSum[mi*16 + r15];   // per-token (col=r15) reciprocal
      size_t rowbase = (size_t)(bt0 + mi*16 + r15)*TD;
      #pragma unroll
      for (int nf=0; nf<8; ++nf){
        f32x4 z = {0,0,0,0};
        f32x4 acc = __builtin_amdgcn_mfma_f32_16x16x32_bf16(bfr[nf], af, z, 0,0,0);
        int d4 = wv*256 + (h*8 + nf)*16 + kg*4;
        size_t idx = rowbase + d4;
        ushort4 xv = *(const ushort4*)(xb + idx);
        ushort4 gv = *(const ushort4*)(gy + idx);
        ushort4 o;
        o.x = f2b(b2f(xv.x) + b2f(gv.x)*acc[0]*rsv);
        o.y = f2b(b2f(xv.y) + b2f(gv.y)*acc[1]*rsv);
        o.z = f2b(b2f(xv.z) + b2f(gv.z)*acc[2]*rsv);
        o.w = f2b(b2f(xv.w) + b2f(gv.w)*acc[3]*rsv);
        *(ushort4*)(gy + idx) = o;
      }
    }
  }
}

extern "C" void kernel_launch(void* const* d_in, const int* in_sizes, int n_in,
                              void* d_out, int out_size, void* d_ws, size_t ws_size,
                              hipStream_t stream){
  const float* x   = (const float*)d_in[0];
  const float* gw  = (const float*)d_in[1];
  const float* gb  = (const float*)d_in[2];
  const float* rqw = (const float*)d_in[3];
  const float* rkw = (const float*)d_in[4];
  const float* rvw = (const float*)d_in[5];
  const float* ow  = (const float*)d_in[6];
  const float* ms  = (const float*)d_in[7];
  const float* wqw = (const float*)d_in[8];
  const float* wkw = (const float*)d_in[9];
  const float* wvw = (const float*)d_in[10];
  float* out = (float*)d_out;
  float* mem_out = out + (size_t)BT*TD;

  // xb (bf16 copy of x, 64MB) lives in the front of d_out: dead before the
  // final GEMM writes out over it.
  u16* xb = (u16*)d_out;

  char* w = (char*)d_ws;
  u16*   gy    = (u16*)(w);                    // 64MB  (g = sigmoid(h), overwritten with y)
  float* wqkb  = (float*)(w + 67108864);       // 128KB
  float* qb    = (float*)(w + 67239936);       // 128KB
  float* qkb   = (float*)(w + 67371008);       // 128KB
  float* xbarb = (float*)(w + 67502080);       // 512KB
  float* memb  = (float*)(w + 68026368);       // 512KB
  float* rkbf  = (float*)(w + 68550656);       // 512KB
  u16*   rkb   = (u16*)(w + 69074944);         // 256KB
  u16*   rvT   = (u16*)(w + 69337088);         // 256KB
  u16*   gwb   = (u16*)(w + 69599232);         // 2MB
  u16*   owb   = (u16*)(w + 71696384);         // 2MB

  k_convw2<<<2048,256,0,stream>>>(gw, ow, gwb, owb);
  k_prep_q<<<dim3(4,32),256,0,stream>>>(ms, wqw, qb);
  k_prep_qk<<<dim3(32,4),256,0,stream>>>(qb, wkw, qkb);
  k_conv_dot<<<512,256,0,stream>>>(x, qkb, xb, wqkb);
  k_wattn<<<dim3(128,4),256,0,stream>>>(wqkb, xb, xbarb);
  // memory = xbar @ Wv^T   (also written to output slot 1)
  k_mm<<<dim3(64,4),256,0,stream>>>(xbarb, wvw, 1, 1.f, memb, mem_out, nullptr, nullptr);
  // rk = memory @ Wrk^T ; rv = memory @ Wrv^T -> transposed bf16 [b][d][s]
  k_mm23<<<dim3(64,4,2),256,0,stream>>>(memb, rkw, rvw, rkbf, rvT);
  // rk~ = scale * rk @ Wrq -> bf16 [b*s][d]
  k_mm<<<dim3(64,4),256,0,stream>>>(rkbf, rqw, 0, 1.f/32.f, nullptr, nullptr, rkb, nullptr);
  // g = sigmoid(x @ gate_w^T + gate_b)
  k_gemm<true><<<2048,256,0,stream>>>(xb, gwb, gb, gy);
  // y = x + g * read   (in place over gy)
  k_read<<<512,256,0,stream>>>(xb, gy, rkb, rvT);
  // out = y @ output_w^T
  k_gemm<false><<<2048,256,0,stream>>>(gy, owb, nullptr, d_out);
}

// Round 3
// 538.076 us; speedup vs baseline: 1.2447x; 1.0667x over previous
//
#include <hip/hip_runtime.h>
#include <stdint.h>

// Problem constants
#define TB 4
#define TT 8192
#define TD 1024
#define TS 32
#define TL 256
#define BT 32768   // TB*TT

typedef unsigned short u16;
typedef __bf16 bf16x8 __attribute__((ext_vector_type(8)));
typedef float f32x4 __attribute__((ext_vector_type(4)));

typedef uint32_t u32_g __attribute__((address_space(1)));
typedef uint32_t u32_l __attribute__((address_space(3)));

#define VMWAIT(N) asm volatile("s_waitcnt vmcnt(" #N ")" ::: "memory")
#define BARRIER() asm volatile("s_barrier" ::: "memory")

__device__ __forceinline__ u16 f2b(float f){
  union { float f; uint32_t u; } a; a.f = f;
  uint32_t r = a.u + 0x7FFFu + ((a.u >> 16) & 1u);
  return (u16)(r >> 16);
}
__device__ __forceinline__ float b2f(u16 u){
  union { uint32_t u; float f; } a; a.u = ((uint32_t)u) << 16;
  return a.f;
}
__device__ __forceinline__ void gll16(const void* g, void* l){
  __builtin_amdgcn_global_load_lds((const u32_g*)g, (u32_l*)l, 16, 0, 0);
}

// ---- convert both f32 weight matrices -> bf16 in one launch ----
__global__ void k_convw2(const float* __restrict__ a, const float* __restrict__ b,
                         u16* __restrict__ oa, u16* __restrict__ ob){
  int i = blockIdx.x*256 + threadIdx.x;   // 0 .. 524287
  const float* src; u16* dst; int j;
  if (i < 262144){ src = a; dst = oa; j = i; }
  else           { src = b; dst = ob; j = i - 262144; }
  float4 v = ((const float4*)src)[j];
  ushort4 u; u.x=f2b(v.x); u.y=f2b(v.y); u.z=f2b(v.z); u.w=f2b(v.w);
  ((ushort4*)dst)[j] = u;
}

// ---- q[s,d] = sum_e ms[s,e] * Wq[d,e] ----
__global__ void k_prep_q(const float* __restrict__ ms, const float* __restrict__ Wq,
                         float* __restrict__ q){
  __shared__ float sm[TD];
  int s = blockIdx.y;
  int d = blockIdx.x*256 + threadIdx.x;
  for (int i = threadIdx.x; i < TD; i += 256) sm[i] = ms[s*TD + i];
  __syncthreads();
  const float* w = Wq + (size_t)d*TD;
  float a0=0.f, a1=0.f;
  for (int e=0; e<TD; e+=8){
    float4 w0 = *(const float4*)(w+e);
    float4 w1 = *(const float4*)(w+e+4);
    a0 += w0.x*sm[e]   + w0.y*sm[e+1] + w0.z*sm[e+2] + w0.w*sm[e+3];
    a1 += w1.x*sm[e+4] + w1.y*sm[e+5] + w1.z*sm[e+6] + w1.w*sm[e+7];
  }
  q[(size_t)s*TD + d] = a0 + a1;
}

// ---- qk[s,e] = scale * sum_d q[s,d] * Wk[d,e]  -- grid (32 s, 4 e-chunks), d split 4-way ----
__global__ void k_prep_qk(const float* __restrict__ q, const float* __restrict__ Wk,
                          float* __restrict__ qk){
  __shared__ float sq[TD];
  __shared__ f32x4 part[4][64];
  int s = blockIdx.x;
  int tid = threadIdx.x;
  int ds = tid >> 6, e4 = tid & 63;
  int e = blockIdx.y*256 + e4*4;
  for (int i = tid; i < TD; i += 256) sq[i] = q[s*TD + i];
  __syncthreads();
  f32x4 acc = {0,0,0,0};
  int d0 = ds*256;
  #pragma unroll 4
  for (int d = d0; d < d0+256; ++d){
    float4 w = *(const float4*)(Wk + (size_t)d*TD + e);
    float sv = sq[d];
    acc[0] += sv*w.x; acc[1] += sv*w.y; acc[2] += sv*w.z; acc[3] += sv*w.w;
  }
  part[ds][e4] = acc;
  __syncthreads();
  if (ds == 0){
    f32x4 t = part[0][e4];
    f32x4 t1 = part[1][e4], t2 = part[2][e4], t3 = part[3][e4];
    const float scale = 1.0f/32.0f;
    float4 o;
    o.x = (t[0]+t1[0]+t2[0]+t3[0])*scale;
    o.y = (t[1]+t1[1]+t2[1]+t3[1])*scale;
    o.z = (t[2]+t1[2]+t2[2]+t3[2])*scale;
    o.w = (t[3]+t1[3]+t2[3]+t3[3])*scale;
    *(float4*)(qk + (size_t)s*TD + e) = o;
  }
}

// ---- single pass over x: convert to bf16 AND compute write logits wqk[bt] ----
// 2048 blocks x 16 tokens (was 512x64: only 2 blocks/CU, latency-bound)
__global__ void k_conv_dot(const float* __restrict__ x, const float* __restrict__ qk,
                           u16* __restrict__ xb, float* __restrict__ wqk){
  int lane = threadIdx.x & 63, wv = threadIdx.x >> 6;
  long bt0 = (long)blockIdx.x * 16;
  int sseg = (int)((bt0 & (TT-1)) >> 8);   // uniform across block (16 | 256)
  float qv[16];
  #pragma unroll
  for (int i=0;i<4;i++){
    float4 t = *(const float4*)(qk + (size_t)sseg*TD + i*256 + lane*4);
    qv[i*4+0]=t.x; qv[i*4+1]=t.y; qv[i*4+2]=t.z; qv[i*4+3]=t.w;
  }
  for (int tok = wv; tok < 16; tok += 4){
    long bt = bt0 + tok;
    const float* xr = x + bt*TD;
    float dot = 0.f;
    #pragma unroll
    for (int i=0;i<4;i++){
      float4 t = *(const float4*)(xr + i*256 + lane*4);
      ushort4 u; u.x=f2b(t.x); u.y=f2b(t.y); u.z=f2b(t.z); u.w=f2b(t.w);
      *(ushort4*)(xb + bt*TD + i*256 + lane*4) = u;
      dot += t.x*qv[i*4] + t.y*qv[i*4+1] + t.z*qv[i*4+2] + t.w*qv[i*4+3];
    }
    #pragma unroll
    for (int o=32;o;o>>=1) dot += __shfl_xor(dot, o);
    if (lane == 0) wqk[bt] = dot;
  }
}

// ---- per (b,s,dchunk): recompute softmax (cheap), accumulate xbar d-slice ----
__global__ void k_wattn(const float* __restrict__ wqk, const u16* __restrict__ xb,
                        float* __restrict__ xbar){
  __shared__ float sw[TL];
  __shared__ float red[8];
  int tid = threadIdx.x, lane = tid & 63, wv = tid >> 6;
  int b = blockIdx.x >> 5, s = blockIdx.x & 31;
  long base = (long)b*TT + (long)s*TL;
  float v = wqk[base + tid];
  float m = v;
  #pragma unroll
  for (int o=32;o;o>>=1) m = fmaxf(m, __shfl_xor(m, o));
  if (lane == 0) red[wv] = m;
  __syncthreads();
  m = fmaxf(fmaxf(red[0], red[1]), fmaxf(red[2], red[3]));
  float e = __expf(v - m);
  float sm = e;
  #pragma unroll
  for (int o=32;o;o>>=1) sm += __shfl_xor(sm, o);
  if (lane == 0) red[4+wv] = sm;
  __syncthreads();
  sm = red[4]+red[5]+red[6]+red[7];
  sw[tid] = e / sm;
  __syncthreads();
  int d = blockIdx.y*256 + tid;
  const u16* xp = xb + base*TD + d;
  float acc = 0.f;
  #pragma unroll 8
  for (int l=0; l<TL; ++l){
    acc += sw[l]*b2f(xp[(size_t)l*TD]);
  }
  xbar[((size_t)b*TS + s)*TD + d] = acc;
}

// ---- small matmul: C[128,1024] = A[128,1024] @ (modeT ? W^T : W), multi-format output ----
__global__ void k_mm(const float* __restrict__ A, const float* __restrict__ W,
                     int modeT, float scale,
                     float* __restrict__ Cf, float* __restrict__ Cf2,
                     u16* __restrict__ Cb, u16* __restrict__ CbT){
  __shared__ float sA[2][TD];
  int r0 = blockIdx.x*2;
  int n = blockIdx.y*256 + threadIdx.x;
  for (int i=threadIdx.x; i<2*TD; i+=256) sA[i>>10][i&1023] = A[(size_t)r0*TD + i];
  __syncthreads();
  float acc0=0.f, acc1=0.f;
  if (modeT){
    const float* w = W + (size_t)n*TD;
    for (int k=0;k<TD;k+=4){
      float4 wv = *(const float4*)(w+k);
      float4 a0 = *(const float4*)(&sA[0][k]);
      float4 a1 = *(const float4*)(&sA[1][k]);
      acc0 += wv.x*a0.x + wv.y*a0.y + wv.z*a0.z + wv.w*a0.w;
      acc1 += wv.x*a1.x + wv.y*a1.y + wv.z*a1.z + wv.w*a1.w;
    }
  } else {
    for (int k=0;k<TD;k+=4){
      float w0 = W[(size_t)k*TD + n],     w1 = W[(size_t)(k+1)*TD + n];
      float w2 = W[(size_t)(k+2)*TD + n], w3 = W[(size_t)(k+3)*TD + n];
      float4 a0 = *(const float4*)(&sA[0][k]);
      float4 a1 = *(const float4*)(&sA[1][k]);
      acc0 += w0*a0.x + w1*a0.y + w2*a0.z + w3*a0.w;
      acc1 += w0*a1.x + w1*a1.y + w2*a1.z + w3*a1.w;
    }
  }
  #pragma unroll
  for (int r=0;r<2;r++){
    float v = (r==0?acc0:acc1)*scale;
    int rr = r0 + r;
    size_t idx = (size_t)rr*TD + n;
    if (Cf)  Cf[idx]  = v;
    if (Cf2) Cf2[idx] = v;
    if (Cb)  Cb[idx]  = f2b(v);
    if (CbT){ int bb = rr >> 5, ss = rr & 31; CbT[((size_t)bb*TD + n)*TS + ss] = f2b(v); }
  }
}

// ---- merged rk/rv matmuls (same A=memory, modeT): z=0 -> rkbf f32, z=1 -> rvT bf16 transposed ----
__global__ void k_mm23(const float* __restrict__ A, const float* __restrict__ W0,
                       const float* __restrict__ W1,
                       float* __restrict__ rkbf, u16* __restrict__ rvT){
  __shared__ float sA[2][TD];
  const float* W = blockIdx.z ? W1 : W0;
  int r0 = blockIdx.x*2;
  int n = blockIdx.y*256 + threadIdx.x;
  for (int i=threadIdx.x; i<2*TD; i+=256) sA[i>>10][i&1023] = A[(size_t)r0*TD + i];
  __syncthreads();
  float acc0=0.f, acc1=0.f;
  const float* w = W + (size_t)n*TD;
  for (int k=0;k<TD;k+=4){
    float4 wv = *(const float4*)(w+k);
    float4 a0 = *(const float4*)(&sA[0][k]);
    float4 a1 = *(const float4*)(&sA[1][k]);
    acc0 += wv.x*a0.x + wv.y*a0.y + wv.z*a0.z + wv.w*a0.w;
    acc1 += wv.x*a1.x + wv.y*a1.y + wv.z*a1.z + wv.w*a1.w;
  }
  #pragma unroll
  for (int r=0;r<2;r++){
    float v = (r==0?acc0:acc1);
    int rr = r0 + r;
    if (blockIdx.z == 0){
      rkbf[(size_t)rr*TD + n] = v;
    } else {
      int bb = rr >> 5, ss = rr & 31;
      rvT[((size_t)bb*TD + n)*TS + ss] = f2b(v);
    }
  }
}

// ---- big MFMA GEMM: C[32768,1024] = A @ W^T  (A bf16 [M][K], W bf16 [N][K]) ----
// 256x256 tile, 512 threads (8 waves 2x4), BK=32, 4-slot LDS ring (128KB),
// counted vmcnt (never 0 in loop), XOR-swizzled LDS, setprio around MFMA.
// LDS slot: [A 16KB | B 16KB]; A/B tile = 256 rows x 32 k bf16 (64B/row).
// swizzle: phys_byte = (row*64 + kh*16) ^ ((row&7)<<4), kh = k/8.
template<bool SIG>
__global__ __launch_bounds__(512, 2) void k_gemm(const u16* __restrict__ A, const u16* __restrict__ Bw,
                                                 const float* __restrict__ bias, void* __restrict__ Cp){
  __shared__ __align__(16) char sL[131072];
  int tid = threadIdx.x, lane = tid & 63, wv = tid >> 6;
  int bid = blockIdx.x;
  int wg = ((bid & 7) << 6) | (bid >> 3);   // XCD swizzle, 512 % 8 == 0 -> bijective
  int nt = wg & 3, mt = wg >> 2;
  int m0 = mt*256, n0 = nt*256;
  int wr = wv >> 2, wc = wv & 3;            // wave -> (m-half, n-quarter)
  int r15 = lane & 15, kg = lane >> 4;

  // LDS read byte-offsets (swizzled), constant over K-loop
  int ard[8], brd[4];
  #pragma unroll
  for (int i=0;i<8;i++){ int row = wr*128 + i*16 + r15; ard[i] = (row*64 + kg*16) ^ ((row&7)<<4); }
  #pragma unroll
  for (int j=0;j<4;j++){ int row = wc*64  + j*16 + r15; brd[j] = (row*64 + kg*16) ^ ((row&7)<<4); }

  // stage: linear LDS dest (gll16 = uniform base + lane*16); pre-inverse-swizzled global source.
  // 16B-slot index S = (r*8+wv)*64 + lane; invert phys->(row,kh):
  const u16* asrc[2]; const u16* bsrc[2]; int ldst[2];
  #pragma unroll
  for (int r=0;r<2;r++){
    int S  = (r*8 + wv)*64 + lane;
    int r1 = (S>>3)&1, r2 = (S>>4)&1;
    int r0 = ((S>>2)&1) ^ r2;
    int row = ((S>>3)<<1) | r0;
    int kh  = (S&3) ^ ((r1<<1) | r0);
    asrc[r] = A  + (size_t)(m0 + row)*TD + kh*8;
    bsrc[r] = Bw + (size_t)(n0 + row)*TD + kh*8;
    ldst[r] = (r*8 + wv)*1024;
  }

  f32x4 acc[8][4];
  #pragma unroll
  for (int i=0;i<8;i++){
    #pragma unroll
    for (int j=0;j<4;j++){ f32x4 z = {0,0,0,0}; acc[i][j] = z; }
  }

  auto stage = [&](int t){
    char* slot = sL + (size_t)(t&3)*32768;
    int k0 = t*32;
    gll16(asrc[0] + k0, slot + ldst[0]);
    gll16(asrc[1] + k0, slot + ldst[1]);
    gll16(bsrc[0] + k0, slot + 16384 + ldst[0]);
    gll16(bsrc[1] + k0, slot + 16384 + ldst[1]);
  };
  auto compute = [&](int t){
    const char* sa = sL + (size_t)(t&3)*32768;
    const char* sb = sa + 16384;
    bf16x8 af[8], bfg[4];
    #pragma unroll
    for (int j=0;j<4;j++) bfg[j] = *(const bf16x8*)(sb + brd[j]);
    #pragma unroll
    for (int i=0;i<8;i++) af[i] = *(const bf16x8*)(sa + ard[i]);
    __builtin_amdgcn_s_setprio(1);
    #pragma unroll
    for (int i=0;i<8;i++){
      #pragma unroll
      for (int j=0;j<4;j++)
        acc[i][j] = __builtin_amdgcn_mfma_f32_16x16x32_bf16(af[i], bfg[j], acc[i][j], 0,0,0);
    }
    __builtin_amdgcn_s_setprio(0);
  };

  // NT = 32 K-tiles. Ring: stage(t+3) targets slot (t-1)&3, retired by iter t-1's end barrier.
  stage(0); stage(1); stage(2);          // 12 loads in flight
  for (int t=0; t<29; ++t){
    stage(t+3);                          // 16 in flight
    VMWAIT(12); BARRIER();               // tile t landed (t+1..t+3 = 12 remain)
    compute(t);
    BARRIER();                           // retire slot t&3 reads
  }
  VMWAIT(8); BARRIER(); compute(29);
  VMWAIT(4); BARRIER(); compute(30);
  VMWAIT(0); BARRIER(); compute(31);

  // epilogue: C row = kg*4+q, col = r15 (round-1-verified mapping)
  #pragma unroll
  for (int i=0;i<8;i++){
    int mrow = m0 + wr*128 + i*16 + kg*4;
    #pragma unroll
    for (int j=0;j<4;j++){
      int n = n0 + wc*64 + j*16 + r15;
      float bj = SIG ? bias[n] : 0.f;
      #pragma unroll
      for (int q=0;q<4;q++){
        float v = acc[i][j][q] + bj;
        size_t idx = (size_t)(mrow + q)*TD + n;
        if (SIG) ((u16*)Cp)[idx] = f2b(1.f/(1.f + __expf(-v)));
        else     ((float*)Cp)[idx] = v;
      }
    }
  }
}

// ---- fused read attention: logits (MFMA) -> masked softmax -> PV (MFMA) -> y = x + g*read ----
// PV uses mfma(V,P) so each lane holds 4 consecutive d -> ushort4 epilogue. y overwrites gy.
__global__ __launch_bounds__(256) void k_read(const u16* __restrict__ xb, u16* __restrict__ gy,
                                              const u16* __restrict__ rkb, const u16* __restrict__ rvT){
  __shared__ __align__(16) u16 sP[64*32];
  __shared__ float sSum[64];
  int tid = threadIdx.x, lane = tid & 63, wv = tid >> 6;
  long bt0 = (long)blockIdx.x * 64;
  int b = (int)(bt0 >> 13);
  int smin = (int)((bt0 & (TT-1)) >> 8);
  int r15 = lane & 15, kg = lane >> 4;

  // QK: wave handles 16 tokens; mfma(x-tokens, rk-slots): row=token(4kg+q), col=slot(r15)
  {
    long tw = bt0 + wv*16;
    const u16* ap  = xb  + (size_t)(tw + r15)*TD + kg*8;
    const u16* bp0 = rkb + ((size_t)(b*TS + r15))*TD + kg*8;
    const u16* bp1 = rkb + ((size_t)(b*TS + 16 + r15))*TD + kg*8;
    f32x4 p0 = {0,0,0,0}, p1 = {0,0,0,0};
    #pragma unroll 4
    for (int ks=0; ks<32; ++ks){
      bf16x8 a  = *(const bf16x8*)(ap  + ks*32);
      bf16x8 b0 = *(const bf16x8*)(bp0 + ks*32);
      bf16x8 b1 = *(const bf16x8*)(bp1 + ks*32);
      p0 = __builtin_amdgcn_mfma_f32_16x16x32_bf16(a, b0, p0, 0,0,0);
      p1 = __builtin_amdgcn_mfma_f32_16x16x32_bf16(a, b1, p1, 0,0,0);
    }
    bool msk0 = (r15 < smin), msk1 = (16 + r15 < smin);
    #pragma unroll
    for (int q=0;q<4;q++){
      float l0 = msk0 ? -1e30f : p0[q];
      float l1 = msk1 ? -1e30f : p1[q];
      float mx = fmaxf(l0, l1);
      #pragma unroll
      for (int o=1;o<16;o<<=1) mx = fmaxf(mx, __shfl_xor(mx, o));
      float e0 = msk0 ? 0.f : __expf(l0 - mx);
      float e1 = msk1 ? 0.f : __expf(l1 - mx);
      float smv = e0 + e1;
      #pragma unroll
      for (int o=1;o<16;o<<=1) smv += __shfl_xor(smv, o);
      int trow = wv*16 + 4*kg + q;
      sP[trow*32 + r15]      = f2b(e0);
      sP[trow*32 + 16 + r15] = f2b(e1);
      if (r15 == 0) sSum[trow] = smv;
    }
  }
  __syncthreads();

  // PV: wave handles d-slice [wv*256, wv*256+256); mfma(V,P): row=d(kg*4+q), col=token(r15)
  int dbase = wv*256 + r15;
  #pragma unroll
  for (int h=0; h<2; ++h){
    bf16x8 bfr[8];
    #pragma unroll
    for (int nf=0; nf<8; ++nf){
      int d = dbase + (h*8 + nf)*16;
      bfr[nf] = *(const bf16x8*)(rvT + ((size_t)b*TD + d)*TS + kg*8);
    }
    #pragma unroll
    for (int mi=0; mi<4; ++mi){
      bf16x8 af = *(const bf16x8*)(sP + (mi*16 + r15)*32 + kg*8);
      float rsv = 1.f / sSum[mi*16 + r15];   // per-token (col=r15) reciprocal
      size_t rowbase = (size_t)(bt0 + mi*16 + r15)*TD;
      #pragma unroll
      for (int nf=0; nf<8; ++nf){
        f32x4 z = {0,0,0,0};
        f32x4 acc = __builtin_amdgcn_mfma_f32_16x16x32_bf16(bfr[nf], af, z, 0,0,0);
        int d4 = wv*256 + (h*8 + nf)*16 + kg*4;
        size_t idx = rowbase + d4;
        ushort4 xv = *(const ushort4*)(xb + idx);
        ushort4 gv = *(const ushort4*)(gy + idx);
        ushort4 o;
        o.x = f2b(b2f(xv.x) + b2f(gv.x)*acc[0]*rsv);
        o.y = f2b(b2f(xv.y) + b2f(gv.y)*acc[1]*rsv);
        o.z = f2b(b2f(xv.z) + b2f(gv.z)*acc[2]*rsv);
        o.w = f2b(b2f(xv.w) + b2f(gv.w)*acc[3]*rsv);
        *(ushort4*)(gy + idx) = o;
      }
    }
  }
}

extern "C" void kernel_launch(void* const* d_in, const int* in_sizes, int n_in,
                              void* d_out, int out_size, void* d_ws, size_t ws_size,
                              hipStream_t stream){
  const float* x   = (const float*)d_in[0];
  const float* gw  = (const float*)d_in[1];
  const float* gb  = (const float*)d_in[2];
  const float* rqw = (const float*)d_in[3];
  const float* rkw = (const float*)d_in[4];
  const float* rvw = (const float*)d_in[5];
  const float* ow  = (const float*)d_in[6];
  const float* ms  = (const float*)d_in[7];
  const float* wqw = (const float*)d_in[8];
  const float* wkw = (const float*)d_in[9];
  const float* wvw = (const float*)d_in[10];
  float* out = (float*)d_out;
  float* mem_out = out + (size_t)BT*TD;

  // xb (bf16 copy of x, 64MB) lives in the front of d_out: dead before the
  // final GEMM writes out over it.
  u16* xb = (u16*)d_out;

  char* w = (char*)d_ws;
  u16*   gy    = (u16*)(w);                    // 64MB  (g = sigmoid(h), overwritten with y)
  float* wqkb  = (float*)(w + 67108864);       // 128KB
  float* qb    = (float*)(w + 67239936);       // 128KB
  float* qkb   = (float*)(w + 67371008);       // 128KB
  float* xbarb = (float*)(w + 67502080);       // 512KB
  float* memb  = (float*)(w + 68026368);       // 512KB
  float* rkbf  = (float*)(w + 68550656);       // 512KB
  u16*   rkb   = (u16*)(w + 69074944);         // 256KB
  u16*   rvT   = (u16*)(w + 69337088);         // 256KB
  u16*   gwb   = (u16*)(w + 69599232);         // 2MB
  u16*   owb   = (u16*)(w + 71696384);         // 2MB

  k_convw2<<<2048,256,0,stream>>>(gw, ow, gwb, owb);
  k_prep_q<<<dim3(4,32),256,0,stream>>>(ms, wqw, qb);
  k_prep_qk<<<dim3(32,4),256,0,stream>>>(qb, wkw, qkb);
  k_conv_dot<<<2048,256,0,stream>>>(x, qkb, xb, wqkb);
  k_wattn<<<dim3(128,4),256,0,stream>>>(wqkb, xb, xbarb);
  // memory = xbar @ Wv^T   (also written to output slot 1)
  k_mm<<<dim3(64,4),256,0,stream>>>(xbarb, wvw, 1, 1.f, memb, mem_out, nullptr, nullptr);
  // rk = memory @ Wrk^T ; rv = memory @ Wrv^T -> transposed bf16 [b][d][s]
  k_mm23<<<dim3(64,4,2),256,0,stream>>>(memb, rkw, rvw, rkbf, rvT);
  // rk~ = scale * rk @ Wrq -> bf16 [b*s][d]
  k_mm<<<dim3(64,4),256,0,stream>>>(rkbf, rqw, 0, 1.f/32.f, nullptr, nullptr, rkb, nullptr);
  // g = sigmoid(x @ gate_w^T + gate_b)
  k_gemm<true><<<512,512,0,stream>>>(xb, gwb, gb, gy);
  // y = x + g * read   (in place over gy)
  k_read<<<512,256,0,stream>>>(xb, gy, rkb, rvT);
  // out = y @ output_w^T
  k_gemm<false><<<512,512,0,stream>>>(gy, owb, nullptr, d_out);
}

// Round 4
// 528.615 us; speedup vs baseline: 1.2670x; 1.0179x over previous
//
#include <hip/hip_runtime.h>
#include <stdint.h>

// Problem constants
#define TB 4
#define TT 8192
#define TD 1024
#define TS 32
#define TL 256
#define BT 32768   // TB*TT

typedef unsigned short u16;
typedef __bf16 bf16x8 __attribute__((ext_vector_type(8)));
typedef float f32x4 __attribute__((ext_vector_type(4)));

typedef uint32_t u32_g __attribute__((address_space(1)));
typedef uint32_t u32_l __attribute__((address_space(3)));

#define VMWAIT(N) asm volatile("s_waitcnt vmcnt(" #N ")" ::: "memory")
#define LGKM0()   asm volatile("s_waitcnt lgkmcnt(0)" ::: "memory")

__device__ __forceinline__ u16 f2b(float f){
  union { float f; uint32_t u; } a; a.f = f;
  uint32_t r = a.u + 0x7FFFu + ((a.u >> 16) & 1u);
  return (u16)(r >> 16);
}
__device__ __forceinline__ float b2f(u16 u){
  union { uint32_t u; float f; } a; a.u = ((uint32_t)u) << 16;
  return a.f;
}
__device__ __forceinline__ void gll16(const void* g, void* l){
  __builtin_amdgcn_global_load_lds((const u32_g*)g, (u32_l*)l, 16, 0, 0);
}

// ---- convert both f32 weight matrices -> bf16 in one launch ----
__global__ void k_convw2(const float* __restrict__ a, const float* __restrict__ b,
                         u16* __restrict__ oa, u16* __restrict__ ob){
  int i = blockIdx.x*256 + threadIdx.x;   // 0 .. 524287
  const float* src; u16* dst; int j;
  if (i < 262144){ src = a; dst = oa; j = i; }
  else           { src = b; dst = ob; j = i - 262144; }
  float4 v = ((const float4*)src)[j];
  ushort4 u; u.x=f2b(v.x); u.y=f2b(v.y); u.z=f2b(v.z); u.w=f2b(v.w);
  ((ushort4*)dst)[j] = u;
}

// ---- q[s,d] = sum_e ms[s,e] * Wq[d,e] ----
__global__ void k_prep_q(const float* __restrict__ ms, const float* __restrict__ Wq,
                         float* __restrict__ q){
  __shared__ float sm[TD];
  int s = blockIdx.y;
  int d = blockIdx.x*256 + threadIdx.x;
  for (int i = threadIdx.x; i < TD; i += 256) sm[i] = ms[s*TD + i];
  __syncthreads();
  const float* w = Wq + (size_t)d*TD;
  float a0=0.f, a1=0.f;
  for (int e=0; e<TD; e+=8){
    float4 w0 = *(const float4*)(w+e);
    float4 w1 = *(const float4*)(w+e+4);
    a0 += w0.x*sm[e]   + w0.y*sm[e+1] + w0.z*sm[e+2] + w0.w*sm[e+3];
    a1 += w1.x*sm[e+4] + w1.y*sm[e+5] + w1.z*sm[e+6] + w1.w*sm[e+7];
  }
  q[(size_t)s*TD + d] = a0 + a1;
}

// ---- qk[s,e] = scale * sum_d q[s,d] * Wk[d,e]  -- grid (32 s, 4 e-chunks), d split 4-way ----
__global__ void k_prep_qk(const float* __restrict__ q, const float* __restrict__ Wk,
                          float* __restrict__ qk){
  __shared__ float sq[TD];
  __shared__ f32x4 part[4][64];
  int s = blockIdx.x;
  int tid = threadIdx.x;
  int ds = tid >> 6, e4 = tid & 63;
  int e = blockIdx.y*256 + e4*4;
  for (int i = tid; i < TD; i += 256) sq[i] = q[s*TD + i];
  __syncthreads();
  f32x4 acc = {0,0,0,0};
  int d0 = ds*256;
  #pragma unroll 4
  for (int d = d0; d < d0+256; ++d){
    float4 w = *(const float4*)(Wk + (size_t)d*TD + e);
    float sv = sq[d];
    acc[0] += sv*w.x; acc[1] += sv*w.y; acc[2] += sv*w.z; acc[3] += sv*w.w;
  }
  part[ds][e4] = acc;
  __syncthreads();
  if (ds == 0){
    f32x4 t = part[0][e4];
    f32x4 t1 = part[1][e4], t2 = part[2][e4], t3 = part[3][e4];
    const float scale = 1.0f/32.0f;
    float4 o;
    o.x = (t[0]+t1[0]+t2[0]+t3[0])*scale;
    o.y = (t[1]+t1[1]+t2[1]+t3[1])*scale;
    o.z = (t[2]+t1[2]+t2[2]+t3[2])*scale;
    o.w = (t[3]+t1[3]+t2[3]+t3[3])*scale;
    *(float4*)(qk + (size_t)s*TD + e) = o;
  }
}

// ---- single pass over x: convert to bf16 AND compute write logits wqk[bt] ----
__global__ void k_conv_dot(const float* __restrict__ x, const float* __restrict__ qk,
                           u16* __restrict__ xb, float* __restrict__ wqk){
  int lane = threadIdx.x & 63, wv = threadIdx.x >> 6;
  long bt0 = (long)blockIdx.x * 16;
  int sseg = (int)((bt0 & (TT-1)) >> 8);   // uniform across block (16 | 256)
  float qv[16];
  #pragma unroll
  for (int i=0;i<4;i++){
    float4 t = *(const float4*)(qk + (size_t)sseg*TD + i*256 + lane*4);
    qv[i*4+0]=t.x; qv[i*4+1]=t.y; qv[i*4+2]=t.z; qv[i*4+3]=t.w;
  }
  for (int tok = wv; tok < 16; tok += 4){
    long bt = bt0 + tok;
    const float* xr = x + bt*TD;
    float dot = 0.f;
    #pragma unroll
    for (int i=0;i<4;i++){
      float4 t = *(const float4*)(xr + i*256 + lane*4);
      ushort4 u; u.x=f2b(t.x); u.y=f2b(t.y); u.z=f2b(t.z); u.w=f2b(t.w);
      *(ushort4*)(xb + bt*TD + i*256 + lane*4) = u;
      dot += t.x*qv[i*4] + t.y*qv[i*4+1] + t.z*qv[i*4+2] + t.w*qv[i*4+3];
    }
    #pragma unroll
    for (int o=32;o;o>>=1) dot += __shfl_xor(dot, o);
    if (lane == 0) wqk[bt] = dot;
  }
}

// ---- per (b,s,dchunk): recompute softmax (cheap), accumulate xbar d-slice ----
__global__ void k_wattn(const float* __restrict__ wqk, const u16* __restrict__ xb,
                        float* __restrict__ xbar){
  __shared__ float sw[TL];
  __shared__ float red[8];
  int tid = threadIdx.x, lane = tid & 63, wv = tid >> 6;
  int b = blockIdx.x >> 5, s = blockIdx.x & 31;
  long base = (long)b*TT + (long)s*TL;
  float v = wqk[base + tid];
  float m = v;
  #pragma unroll
  for (int o=32;o;o>>=1) m = fmaxf(m, __shfl_xor(m, o));
  if (lane == 0) red[wv] = m;
  __syncthreads();
  m = fmaxf(fmaxf(red[0], red[1]), fmaxf(red[2], red[3]));
  float e = __expf(v - m);
  float sm = e;
  #pragma unroll
  for (int o=32;o;o>>=1) sm += __shfl_xor(sm, o);
  if (lane == 0) red[4+wv] = sm;
  __syncthreads();
  sm = red[4]+red[5]+red[6]+red[7];
  sw[tid] = e / sm;
  __syncthreads();
  int d = blockIdx.y*256 + tid;
  const u16* xp = xb + base*TD + d;
  float acc = 0.f;
  #pragma unroll 8
  for (int l=0; l<TL; ++l){
    acc += sw[l]*b2f(xp[(size_t)l*TD]);
  }
  xbar[((size_t)b*TS + s)*TD + d] = acc;
}

// ---- small matmul: C[128,1024] = A[128,1024] @ (modeT ? W^T : W), multi-format output ----
__global__ void k_mm(const float* __restrict__ A, const float* __restrict__ W,
                     int modeT, float scale,
                     float* __restrict__ Cf, float* __restrict__ Cf2,
                     u16* __restrict__ Cb, u16* __restrict__ CbT){
  __shared__ float sA[2][TD];
  int r0 = blockIdx.x*2;
  int n = blockIdx.y*256 + threadIdx.x;
  for (int i=threadIdx.x; i<2*TD; i+=256) sA[i>>10][i&1023] = A[(size_t)r0*TD + i];
  __syncthreads();
  float acc0=0.f, acc1=0.f;
  if (modeT){
    const float* w = W + (size_t)n*TD;
    for (int k=0;k<TD;k+=4){
      float4 wv = *(const float4*)(w+k);
      float4 a0 = *(const float4*)(&sA[0][k]);
      float4 a1 = *(const float4*)(&sA[1][k]);
      acc0 += wv.x*a0.x + wv.y*a0.y + wv.z*a0.z + wv.w*a0.w;
      acc1 += wv.x*a1.x + wv.y*a1.y + wv.z*a1.z + wv.w*a1.w;
    }
  } else {
    for (int k=0;k<TD;k+=4){
      float w0 = W[(size_t)k*TD + n],     w1 = W[(size_t)(k+1)*TD + n];
      float w2 = W[(size_t)(k+2)*TD + n], w3 = W[(size_t)(k+3)*TD + n];
      float4 a0 = *(const float4*)(&sA[0][k]);
      float4 a1 = *(const float4*)(&sA[1][k]);
      acc0 += w0*a0.x + w1*a0.y + w2*a0.z + w3*a0.w;
      acc1 += w0*a1.x + w1*a1.y + w2*a1.z + w3*a1.w;
    }
  }
  #pragma unroll
  for (int r=0;r<2;r++){
    float v = (r==0?acc0:acc1)*scale;
    int rr = r0 + r;
    size_t idx = (size_t)rr*TD + n;
    if (Cf)  Cf[idx]  = v;
    if (Cf2) Cf2[idx] = v;
    if (Cb)  Cb[idx]  = f2b(v);
    if (CbT){ int bb = rr >> 5, ss = rr & 31; CbT[((size_t)bb*TD + n)*TS + ss] = f2b(v); }
  }
}

// ---- merged rk/rv matmuls (same A=memory, modeT): z=0 -> rkbf f32, z=1 -> rvT bf16 transposed ----
__global__ void k_mm23(const float* __restrict__ A, const float* __restrict__ W0,
                       const float* __restrict__ W1,
                       float* __restrict__ rkbf, u16* __restrict__ rvT){
  __shared__ float sA[2][TD];
  const float* W = blockIdx.z ? W1 : W0;
  int r0 = blockIdx.x*2;
  int n = blockIdx.y*256 + threadIdx.x;
  for (int i=threadIdx.x; i<2*TD; i+=256) sA[i>>10][i&1023] = A[(size_t)r0*TD + i];
  __syncthreads();
  float acc0=0.f, acc1=0.f;
  const float* w = W + (size_t)n*TD;
  for (int k=0;k<TD;k+=4){
    float4 wv = *(const float4*)(w+k);
    float4 a0 = *(const float4*)(&sA[0][k]);
    float4 a1 = *(const float4*)(&sA[1][k]);
    acc0 += wv.x*a0.x + wv.y*a0.y + wv.z*a0.z + wv.w*a0.w;
    acc1 += wv.x*a1.x + wv.y*a1.y + wv.z*a1.z + wv.w*a1.w;
  }
  #pragma unroll
  for (int r=0;r<2;r++){
    float v = (r==0?acc0:acc1);
    int rr = r0 + r;
    if (blockIdx.z == 0){
      rkbf[(size_t)rr*TD + n] = v;
    } else {
      int bb = rr >> 5, ss = rr & 31;
      rvT[((size_t)bb*TD + n)*TS + ss] = f2b(v);
    }
  }
}

// ---- big MFMA GEMM: C[32768,1024] = A @ W^T  (A bf16 [M][K], W bf16 [N][K]) ----
// 256x256 tile, 512 threads (8 waves 2x4), BK=32, 4-slot LDS ring (128KB),
// 8-phase-style schedule: per tile 2 phases, each {ds_reads; 2x gll16 stage;
// s_barrier; lgkmcnt(0); setprio(1); 16 MFMA; setprio(0)}; tile-entry
// vmcnt(8) (counted, never 0 until drain) + barrier. XOR-swizzled LDS reads,
// linear gll16 dest with pre-inverse-swizzled global source.
template<bool SIG>
__global__ __launch_bounds__(512, 2) void k_gemm(const u16* __restrict__ A, const u16* __restrict__ Bw,
                                                 const float* __restrict__ bias, void* __restrict__ Cp){
  __shared__ __align__(16) char sL[131072];
  int tid = threadIdx.x, lane = tid & 63, wv = tid >> 6;
  int bid = blockIdx.x;
  int wg = ((bid & 7) << 6) | (bid >> 3);   // XCD swizzle, 512 % 8 == 0 -> bijective
  int nt = wg & 3, mt = wg >> 2;
  int m0 = mt*256, n0 = nt*256;
  int wr = wv >> 2, wc = wv & 3;            // wave -> (m-half, n-quarter)
  int r15 = lane & 15, kg = lane >> 4;

  // LDS read byte-offsets (swizzled), constant over K-loop
  int ard[8], brd[4];
  #pragma unroll
  for (int i=0;i<8;i++){ int row = wr*128 + i*16 + r15; ard[i] = (row*64 + kg*16) ^ ((row&7)<<4); }
  #pragma unroll
  for (int j=0;j<4;j++){ int row = wc*64  + j*16 + r15; brd[j] = (row*64 + kg*16) ^ ((row&7)<<4); }

  // stage: linear LDS dest (gll16 = uniform base + lane*16); pre-inverse-swizzled global source.
  const u16* asrc[2]; const u16* bsrc[2]; int ldst[2];
  #pragma unroll
  for (int r=0;r<2;r++){
    int S  = (r*8 + wv)*64 + lane;
    int r1 = (S>>3)&1, r2 = (S>>4)&1;
    int r0 = ((S>>2)&1) ^ r2;
    int row = ((S>>3)<<1) | r0;
    int kh  = (S&3) ^ ((r1<<1) | r0);
    asrc[r] = A  + (size_t)(m0 + row)*TD + kh*8;
    bsrc[r] = Bw + (size_t)(n0 + row)*TD + kh*8;
    ldst[r] = (r*8 + wv)*1024;
  }

  f32x4 acc[8][4];
  #pragma unroll
  for (int i=0;i<8;i++){
    #pragma unroll
    for (int j=0;j<4;j++){ f32x4 z = {0,0,0,0}; acc[i][j] = z; }
  }

  auto stageA = [&](int t){
    char* slot = sL + (size_t)(t&3)*32768;
    int k0 = t*32;
    gll16(asrc[0] + k0, slot + ldst[0]);
    gll16(asrc[1] + k0, slot + ldst[1]);
  };
  auto stageB = [&](int t){
    char* slot = sL + (size_t)(t&3)*32768;
    int k0 = t*32;
    gll16(bsrc[0] + k0, slot + 16384 + ldst[0]);
    gll16(bsrc[1] + k0, slot + 16384 + ldst[1]);
  };

  // tile body: 2 phases (T3+T4+T5). Stages for tile t+3 issued inside (safe:
  // they target slot (t-1)&3 whose readers retired before the tile-entry barrier).
  auto tile = [&](int t, bool prefetch){
    const char* sa = sL + (size_t)(t&3)*32768;
    const char* sb = sa + 16384;
    // phase 0
    bf16x8 bfg[4], af[4];
    #pragma unroll
    for (int j=0;j<4;j++) bfg[j] = *(const bf16x8*)(sb + brd[j]);
    #pragma unroll
    for (int i=0;i<4;i++) af[i] = *(const bf16x8*)(sa + ard[i]);
    if (prefetch) stageA(t+3);
    __builtin_amdgcn_s_barrier();
    LGKM0();
    __builtin_amdgcn_sched_barrier(0);
    __builtin_amdgcn_s_setprio(1);
    #pragma unroll
    for (int i=0;i<4;i++){
      #pragma unroll
      for (int j=0;j<4;j++)
        acc[i][j] = __builtin_amdgcn_mfma_f32_16x16x32_bf16(af[i], bfg[j], acc[i][j], 0,0,0);
    }
    __builtin_amdgcn_s_setprio(0);
    // phase 1
    bf16x8 af2[4];
    #pragma unroll
    for (int i=0;i<4;i++) af2[i] = *(const bf16x8*)(sa + ard[4+i]);
    if (prefetch) stageB(t+3);
    __builtin_amdgcn_s_barrier();
    LGKM0();
    __builtin_amdgcn_sched_barrier(0);
    __builtin_amdgcn_s_setprio(1);
    #pragma unroll
    for (int i=0;i<4;i++){
      #pragma unroll
      for (int j=0;j<4;j++)
        acc[4+i][j] = __builtin_amdgcn_mfma_f32_16x16x32_bf16(af2[i], bfg[j], acc[4+i][j], 0,0,0);
    }
    __builtin_amdgcn_s_setprio(0);
  };

  // prologue: stage tiles 0,1,2 (12 loads in flight)
  stageA(0); stageB(0); stageA(1); stageB(1); stageA(2); stageB(2);

  for (int t=0; t<30; ++t){
    VMWAIT(8);                          // tile t landed (t+1,t+2 = 8 loads remain)
    __builtin_amdgcn_s_barrier();       // all waves' loads landed; t-1 readers retired
    tile(t, t < 29);
  }
  VMWAIT(4); __builtin_amdgcn_s_barrier(); tile(30, false);
  VMWAIT(0); __builtin_amdgcn_s_barrier(); tile(31, false);

  // epilogue: C row = kg*4+q, col = r15 (round-1-verified mapping)
  #pragma unroll
  for (int i=0;i<8;i++){
    int mrow = m0 + wr*128 + i*16 + kg*4;
    #pragma unroll
    for (int j=0;j<4;j++){
      int n = n0 + wc*64 + j*16 + r15;
      float bj = SIG ? bias[n] : 0.f;
      #pragma unroll
      for (int q=0;q<4;q++){
        float v = acc[i][j][q] + bj;
        size_t idx = (size_t)(mrow + q)*TD + n;
        if (SIG) ((u16*)Cp)[idx] = f2b(1.f/(1.f + __expf(-v)));
        else     ((float*)Cp)[idx] = v;
      }
    }
  }
}

// ---- fused read attention: logits (MFMA) -> masked softmax -> PV (MFMA) -> y = x + g*read ----
// PV uses mfma(V,P) so each lane holds 4 consecutive d -> ushort4 epilogue. y overwrites gy.
__global__ __launch_bounds__(256) void k_read(const u16* __restrict__ xb, u16* __restrict__ gy,
                                              const u16* __restrict__ rkb, const u16* __restrict__ rvT){
  __shared__ __align__(16) u16 sP[64*32];
  __shared__ float sSum[64];
  int tid = threadIdx.x, lane = tid & 63, wv = tid >> 6;
  long bt0 = (long)blockIdx.x * 64;
  int b = (int)(bt0 >> 13);
  int smin = (int)((bt0 & (TT-1)) >> 8);
  int r15 = lane & 15, kg = lane >> 4;

  // QK: wave handles 16 tokens; mfma(x-tokens, rk-slots): row=token(4kg+q), col=slot(r15)
  {
    long tw = bt0 + wv*16;
    const u16* ap  = xb  + (size_t)(tw + r15)*TD + kg*8;
    const u16* bp0 = rkb + ((size_t)(b*TS + r15))*TD + kg*8;
    const u16* bp1 = rkb + ((size_t)(b*TS + 16 + r15))*TD + kg*8;
    f32x4 p0 = {0,0,0,0}, p1 = {0,0,0,0};
    #pragma unroll 4
    for (int ks=0; ks<32; ++ks){
      bf16x8 a  = *(const bf16x8*)(ap  + ks*32);
      bf16x8 b0 = *(const bf16x8*)(bp0 + ks*32);
      bf16x8 b1 = *(const bf16x8*)(bp1 + ks*32);
      p0 = __builtin_amdgcn_mfma_f32_16x16x32_bf16(a, b0, p0, 0,0,0);
      p1 = __builtin_amdgcn_mfma_f32_16x16x32_bf16(a, b1, p1, 0,0,0);
    }
    bool msk0 = (r15 < smin), msk1 = (16 + r15 < smin);
    #pragma unroll
    for (int q=0;q<4;q++){
      float l0 = msk0 ? -1e30f : p0[q];
      float l1 = msk1 ? -1e30f : p1[q];
      float mx = fmaxf(l0, l1);
      #pragma unroll
      for (int o=1;o<16;o<<=1) mx = fmaxf(mx, __shfl_xor(mx, o));
      float e0 = msk0 ? 0.f : __expf(l0 - mx);
      float e1 = msk1 ? 0.f : __expf(l1 - mx);
      float smv = e0 + e1;
      #pragma unroll
      for (int o=1;o<16;o<<=1) smv += __shfl_xor(smv, o);
      int trow = wv*16 + 4*kg + q;
      sP[trow*32 + r15]      = f2b(e0);
      sP[trow*32 + 16 + r15] = f2b(e1);
      if (r15 == 0) sSum[trow] = smv;
    }
  }
  __syncthreads();

  // PV: wave handles d-slice [wv*256, wv*256+256); mfma(V,P): row=d(kg*4+q), col=token(r15)
  int dbase = wv*256 + r15;
  #pragma unroll
  for (int h=0; h<2; ++h){
    bf16x8 bfr[8];
    #pragma unroll
    for (int nf=0; nf<8; ++nf){
      int d = dbase + (h*8 + nf)*16;
      bfr[nf] = *(const bf16x8*)(rvT + ((size_t)b*TD + d)*TS + kg*8);
    }
    #pragma unroll
    for (int mi=0; mi<4; ++mi){
      bf16x8 af = *(const bf16x8*)(sP + (mi*16 + r15)*32 + kg*8);
      float rsv = 1.f / sSum[mi*16 + r15];   // per-token (col=r15) reciprocal
      size_t rowbase = (size_t)(bt0 + mi*16 + r15)*TD;
      #pragma unroll
      for (int nf=0; nf<8; ++nf){
        f32x4 z = {0,0,0,0};
        f32x4 acc = __builtin_amdgcn_mfma_f32_16x16x32_bf16(bfr[nf], af, z, 0,0,0);
        int d4 = wv*256 + (h*8 + nf)*16 + kg*4;
        size_t idx = rowbase + d4;
        ushort4 xv = *(const ushort4*)(xb + idx);
        ushort4 gv = *(const ushort4*)(gy + idx);
        ushort4 o;
        o.x = f2b(b2f(xv.x) + b2f(gv.x)*acc[0]*rsv);
        o.y = f2b(b2f(xv.y) + b2f(gv.y)*acc[1]*rsv);
        o.z = f2b(b2f(xv.z) + b2f(gv.z)*acc[2]*rsv);
        o.w = f2b(b2f(xv.w) + b2f(gv.w)*acc[3]*rsv);
        *(ushort4*)(gy + idx) = o;
      }
    }
  }
}

extern "C" void kernel_launch(void* const* d_in, const int* in_sizes, int n_in,
                              void* d_out, int out_size, void* d_ws, size_t ws_size,
                              hipStream_t stream){
  const float* x   = (const float*)d_in[0];
  const float* gw  = (const float*)d_in[1];
  const float* gb  = (const float*)d_in[2];
  const float* rqw = (const float*)d_in[3];
  const float* rkw = (const float*)d_in[4];
  const float* rvw = (const float*)d_in[5];
  const float* ow  = (const float*)d_in[6];
  const float* ms  = (const float*)d_in[7];
  const float* wqw = (const float*)d_in[8];
  const float* wkw = (const float*)d_in[9];
  const float* wvw = (const float*)d_in[10];
  float* out = (float*)d_out;
  float* mem_out = out + (size_t)BT*TD;

  // xb (bf16 copy of x, 64MB) lives in the front of d_out: dead before the
  // final GEMM writes out over it.
  u16* xb = (u16*)d_out;

  char* w = (char*)d_ws;
  u16*   gy    = (u16*)(w);                    // 64MB  (g = sigmoid(h), overwritten with y)
  float* wqkb  = (float*)(w + 67108864);       // 128KB
  float* qb    = (float*)(w + 67239936);       // 128KB
  float* qkb   = (float*)(w + 67371008);       // 128KB
  float* xbarb = (float*)(w + 67502080);       // 512KB
  float* memb  = (float*)(w + 68026368);       // 512KB
  float* rkbf  = (float*)(w + 68550656);       // 512KB
  u16*   rkb   = (u16*)(w + 69074944);         // 256KB
  u16*   rvT   = (u16*)(w + 69337088);         // 256KB
  u16*   gwb   = (u16*)(w + 69599232);         // 2MB
  u16*   owb   = (u16*)(w + 71696384);         // 2MB

  k_convw2<<<2048,256,0,stream>>>(gw, ow, gwb, owb);
  k_prep_q<<<dim3(4,32),256,0,stream>>>(ms, wqw, qb);
  k_prep_qk<<<dim3(32,4),256,0,stream>>>(qb, wkw, qkb);
  k_conv_dot<<<2048,256,0,stream>>>(x, qkb, xb, wqkb);
  k_wattn<<<dim3(128,4),256,0,stream>>>(wqkb, xb, xbarb);
  // memory = xbar @ Wv^T   (also written to output slot 1)
  k_mm<<<dim3(64,4),256,0,stream>>>(xbarb, wvw, 1, 1.f, memb, mem_out, nullptr, nullptr);
  // rk = memory @ Wrk^T ; rv = memory @ Wrv^T -> transposed bf16 [b][d][s]
  k_mm23<<<dim3(64,4,2),256,0,stream>>>(memb, rkw, rvw, rkbf, rvT);
  // rk~ = scale * rk @ Wrq -> bf16 [b*s][d]
  k_mm<<<dim3(64,4),256,0,stream>>>(rkbf, rqw, 0, 1.f/32.f, nullptr, nullptr, rkb, nullptr);
  // g = sigmoid(x @ gate_w^T + gate_b)
  k_gemm<true><<<512,512,0,stream>>>(xb, gwb, gb, gy);
  // y = x + g * read   (in place over gy)
  k_read<<<512,256,0,stream>>>(xb, gy, rkb, rvT);
  // out = y @ output_w^T
  k_gemm<false><<<512,512,0,stream>>>(gy, owb, nullptr, d_out);
}

// Round 5
// 492.211 us; speedup vs baseline: 1.3607x; 1.0740x over previous
//
#include <hip/hip_runtime.h>
#include <stdint.h>

// Problem constants
#define TB 4
#define TT 8192
#define TD 1024
#define TS 32
#define TL 256
#define BT 32768   // TB*TT

typedef unsigned short u16;
typedef __bf16 bf16x8 __attribute__((ext_vector_type(8)));
typedef float f32x4 __attribute__((ext_vector_type(4)));

typedef uint32_t u32_g __attribute__((address_space(1)));
typedef uint32_t u32_l __attribute__((address_space(3)));

#define VMWAIT(N) asm volatile("s_waitcnt vmcnt(" #N ")" ::: "memory")
#define LGKM0()   asm volatile("s_waitcnt lgkmcnt(0)" ::: "memory")

__device__ __forceinline__ u16 f2b(float f){
  union { float f; uint32_t u; } a; a.f = f;
  uint32_t r = a.u + 0x7FFFu + ((a.u >> 16) & 1u);
  return (u16)(r >> 16);
}
__device__ __forceinline__ float b2f(u16 u){
  union { uint32_t u; float f; } a; a.u = ((uint32_t)u) << 16;
  return a.f;
}
__device__ __forceinline__ void gll16(const void* g, void* l){
  __builtin_amdgcn_global_load_lds((const u32_g*)g, (u32_l*)l, 16, 0, 0);
}

// ---- convert both f32 weight matrices -> bf16 in one launch ----
__global__ void k_convw2(const float* __restrict__ a, const float* __restrict__ b,
                         u16* __restrict__ oa, u16* __restrict__ ob){
  int i = blockIdx.x*256 + threadIdx.x;   // 0 .. 524287
  const float* src; u16* dst; int j;
  if (i < 262144){ src = a; dst = oa; j = i; }
  else           { src = b; dst = ob; j = i - 262144; }
  float4 v = ((const float4*)src)[j];
  ushort4 u; u.x=f2b(v.x); u.y=f2b(v.y); u.z=f2b(v.z); u.w=f2b(v.w);
  ((ushort4*)dst)[j] = u;
}

// ---- q[s,d] = sum_e ms[s,e] * Wq[d,e] ----
__global__ void k_prep_q(const float* __restrict__ ms, const float* __restrict__ Wq,
                         float* __restrict__ q){
  __shared__ float sm[TD];
  int s = blockIdx.y;
  int d = blockIdx.x*256 + threadIdx.x;
  for (int i = threadIdx.x; i < TD; i += 256) sm[i] = ms[s*TD + i];
  __syncthreads();
  const float* w = Wq + (size_t)d*TD;
  float a0=0.f, a1=0.f;
  for (int e=0; e<TD; e+=8){
    float4 w0 = *(const float4*)(w+e);
    float4 w1 = *(const float4*)(w+e+4);
    a0 += w0.x*sm[e]   + w0.y*sm[e+1] + w0.z*sm[e+2] + w0.w*sm[e+3];
    a1 += w1.x*sm[e+4] + w1.y*sm[e+5] + w1.z*sm[e+6] + w1.w*sm[e+7];
  }
  q[(size_t)s*TD + d] = a0 + a1;
}

// ---- qk[s,e] = scale * sum_d q[s,d] * Wk[d,e]  -- grid (32 s, 4 e-chunks), d split 4-way ----
__global__ void k_prep_qk(const float* __restrict__ q, const float* __restrict__ Wk,
                          float* __restrict__ qk){
  __shared__ float sq[TD];
  __shared__ f32x4 part[4][64];
  int s = blockIdx.x;
  int tid = threadIdx.x;
  int ds = tid >> 6, e4 = tid & 63;
  int e = blockIdx.y*256 + e4*4;
  for (int i = tid; i < TD; i += 256) sq[i] = q[s*TD + i];
  __syncthreads();
  f32x4 acc = {0,0,0,0};
  int d0 = ds*256;
  #pragma unroll 4
  for (int d = d0; d < d0+256; ++d){
    float4 w = *(const float4*)(Wk + (size_t)d*TD + e);
    float sv = sq[d];
    acc[0] += sv*w.x; acc[1] += sv*w.y; acc[2] += sv*w.z; acc[3] += sv*w.w;
  }
  part[ds][e4] = acc;
  __syncthreads();
  if (ds == 0){
    f32x4 t = part[0][e4];
    f32x4 t1 = part[1][e4], t2 = part[2][e4], t3 = part[3][e4];
    const float scale = 1.0f/32.0f;
    float4 o;
    o.x = (t[0]+t1[0]+t2[0]+t3[0])*scale;
    o.y = (t[1]+t1[1]+t2[1]+t3[1])*scale;
    o.z = (t[2]+t1[2]+t2[2]+t3[2])*scale;
    o.w = (t[3]+t1[3]+t2[3]+t3[3])*scale;
    *(float4*)(qk + (size_t)s*TD + e) = o;
  }
}

// ---- single pass over x: convert to bf16 AND compute write logits wqk[bt] ----
__global__ void k_conv_dot(const float* __restrict__ x, const float* __restrict__ qk,
                           u16* __restrict__ xb, float* __restrict__ wqk){
  int lane = threadIdx.x & 63, wv = threadIdx.x >> 6;
  long bt0 = (long)blockIdx.x * 16;
  int sseg = (int)((bt0 & (TT-1)) >> 8);   // uniform across block (16 | 256)
  float qv[16];
  #pragma unroll
  for (int i=0;i<4;i++){
    float4 t = *(const float4*)(qk + (size_t)sseg*TD + i*256 + lane*4);
    qv[i*4+0]=t.x; qv[i*4+1]=t.y; qv[i*4+2]=t.z; qv[i*4+3]=t.w;
  }
  for (int tok = wv; tok < 16; tok += 4){
    long bt = bt0 + tok;
    const float* xr = x + bt*TD;
    float dot = 0.f;
    #pragma unroll
    for (int i=0;i<4;i++){
      float4 t = *(const float4*)(xr + i*256 + lane*4);
      ushort4 u; u.x=f2b(t.x); u.y=f2b(t.y); u.z=f2b(t.z); u.w=f2b(t.w);
      *(ushort4*)(xb + bt*TD + i*256 + lane*4) = u;
      dot += t.x*qv[i*4] + t.y*qv[i*4+1] + t.z*qv[i*4+2] + t.w*qv[i*4+3];
    }
    #pragma unroll
    for (int o=32;o;o>>=1) dot += __shfl_xor(dot, o);
    if (lane == 0) wqk[bt] = dot;
  }
}

// ---- per (b,s,dchunk): recompute softmax (cheap), accumulate xbar d-slice ----
__global__ void k_wattn(const float* __restrict__ wqk, const u16* __restrict__ xb,
                        float* __restrict__ xbar){
  __shared__ float sw[TL];
  __shared__ float red[8];
  int tid = threadIdx.x, lane = tid & 63, wv = tid >> 6;
  int b = blockIdx.x >> 5, s = blockIdx.x & 31;
  long base = (long)b*TT + (long)s*TL;
  float v = wqk[base + tid];
  float m = v;
  #pragma unroll
  for (int o=32;o;o>>=1) m = fmaxf(m, __shfl_xor(m, o));
  if (lane == 0) red[wv] = m;
  __syncthreads();
  m = fmaxf(fmaxf(red[0], red[1]), fmaxf(red[2], red[3]));
  float e = __expf(v - m);
  float sm = e;
  #pragma unroll
  for (int o=32;o;o>>=1) sm += __shfl_xor(sm, o);
  if (lane == 0) red[4+wv] = sm;
  __syncthreads();
  sm = red[4]+red[5]+red[6]+red[7];
  sw[tid] = e / sm;
  __syncthreads();
  int d = blockIdx.y*256 + tid;
  const u16* xp = xb + base*TD + d;
  float acc = 0.f;
  #pragma unroll 8
  for (int l=0; l<TL; ++l){
    acc += sw[l]*b2f(xp[(size_t)l*TD]);
  }
  xbar[((size_t)b*TS + s)*TD + d] = acc;
}

// ---- small matmul: C[128,1024] = A[128,1024] @ (modeT ? W^T : W), multi-format output ----
__global__ void k_mm(const float* __restrict__ A, const float* __restrict__ W,
                     int modeT, float scale,
                     float* __restrict__ Cf, float* __restrict__ Cf2,
                     u16* __restrict__ Cb, u16* __restrict__ CbT){
  __shared__ float sA[2][TD];
  int r0 = blockIdx.x*2;
  int n = blockIdx.y*256 + threadIdx.x;
  for (int i=threadIdx.x; i<2*TD; i+=256) sA[i>>10][i&1023] = A[(size_t)r0*TD + i];
  __syncthreads();
  float acc0=0.f, acc1=0.f;
  if (modeT){
    const float* w = W + (size_t)n*TD;
    for (int k=0;k<TD;k+=4){
      float4 wv = *(const float4*)(w+k);
      float4 a0 = *(const float4*)(&sA[0][k]);
      float4 a1 = *(const float4*)(&sA[1][k]);
      acc0 += wv.x*a0.x + wv.y*a0.y + wv.z*a0.z + wv.w*a0.w;
      acc1 += wv.x*a1.x + wv.y*a1.y + wv.z*a1.z + wv.w*a1.w;
    }
  } else {
    for (int k=0;k<TD;k+=4){
      float w0 = W[(size_t)k*TD + n],     w1 = W[(size_t)(k+1)*TD + n];
      float w2 = W[(size_t)(k+2)*TD + n], w3 = W[(size_t)(k+3)*TD + n];
      float4 a0 = *(const float4*)(&sA[0][k]);
      float4 a1 = *(const float4*)(&sA[1][k]);
      acc0 += w0*a0.x + w1*a0.y + w2*a0.z + w3*a0.w;
      acc1 += w0*a1.x + w1*a1.y + w2*a1.z + w3*a1.w;
    }
  }
  #pragma unroll
  for (int r=0;r<2;r++){
    float v = (r==0?acc0:acc1)*scale;
    int rr = r0 + r;
    size_t idx = (size_t)rr*TD + n;
    if (Cf)  Cf[idx]  = v;
    if (Cf2) Cf2[idx] = v;
    if (Cb)  Cb[idx]  = f2b(v);
    if (CbT){ int bb = rr >> 5, ss = rr & 31; CbT[((size_t)bb*TD + n)*TS + ss] = f2b(v); }
  }
}

// ---- merged rk/rv matmuls (same A=memory, modeT): z=0 -> rkbf f32, z=1 -> rvT bf16 transposed ----
__global__ void k_mm23(const float* __restrict__ A, const float* __restrict__ W0,
                       const float* __restrict__ W1,
                       float* __restrict__ rkbf, u16* __restrict__ rvT){
  __shared__ float sA[2][TD];
  const float* W = blockIdx.z ? W1 : W0;
  int r0 = blockIdx.x*2;
  int n = blockIdx.y*256 + threadIdx.x;
  for (int i=threadIdx.x; i<2*TD; i+=256) sA[i>>10][i&1023] = A[(size_t)r0*TD + i];
  __syncthreads();
  float acc0=0.f, acc1=0.f;
  const float* w = W + (size_t)n*TD;
  for (int k=0;k<TD;k+=4){
    float4 wv = *(const float4*)(w+k);
    float4 a0 = *(const float4*)(&sA[0][k]);
    float4 a1 = *(const float4*)(&sA[1][k]);
    acc0 += wv.x*a0.x + wv.y*a0.y + wv.z*a0.z + wv.w*a0.w;
    acc1 += wv.x*a1.x + wv.y*a1.y + wv.z*a1.z + wv.w*a1.w;
  }
  #pragma unroll
  for (int r=0;r<2;r++){
    float v = (r==0?acc0:acc1);
    int rr = r0 + r;
    if (blockIdx.z == 0){
      rkbf[(size_t)rr*TD + n] = v;
    } else {
      int bb = rr >> 5, ss = rr & 31;
      rvT[((size_t)bb*TD + n)*TS + ss] = f2b(v);
    }
  }
}

// ---- read-attention weights: QK^T (MFMA) + masked softmax -> normalized P [BT][32] bf16 ----
__global__ __launch_bounds__(256) void k_pattn(const u16* __restrict__ xb, const u16* __restrict__ rkb,
                                               u16* __restrict__ P){
  int tid = threadIdx.x, lane = tid & 63, wv = tid >> 6;
  long bt0 = (long)blockIdx.x * 64;
  int b = (int)(bt0 >> 13);
  int smin = (int)((bt0 & (TT-1)) >> 8);
  int r15 = lane & 15, kg = lane >> 4;

  long tw = bt0 + wv*16;
  const u16* ap  = xb  + (size_t)(tw + r15)*TD + kg*8;
  const u16* bp0 = rkb + ((size_t)(b*TS + r15))*TD + kg*8;
  const u16* bp1 = rkb + ((size_t)(b*TS + 16 + r15))*TD + kg*8;
  f32x4 p0 = {0,0,0,0}, p1 = {0,0,0,0};
  #pragma unroll 4
  for (int ks=0; ks<32; ++ks){
    bf16x8 a  = *(const bf16x8*)(ap  + ks*32);
    bf16x8 b0 = *(const bf16x8*)(bp0 + ks*32);
    bf16x8 b1 = *(const bf16x8*)(bp1 + ks*32);
    p0 = __builtin_amdgcn_mfma_f32_16x16x32_bf16(a, b0, p0, 0,0,0);
    p1 = __builtin_amdgcn_mfma_f32_16x16x32_bf16(a, b1, p1, 0,0,0);
  }
  bool msk0 = (r15 < smin), msk1 = (16 + r15 < smin);
  #pragma unroll
  for (int q=0;q<4;q++){
    float l0 = msk0 ? -1e30f : p0[q];
    float l1 = msk1 ? -1e30f : p1[q];
    float mx = fmaxf(l0, l1);
    #pragma unroll
    for (int o=1;o<16;o<<=1) mx = fmaxf(mx, __shfl_xor(mx, o));
    float e0 = msk0 ? 0.f : __expf(l0 - mx);
    float e1 = msk1 ? 0.f : __expf(l1 - mx);
    float smv = e0 + e1;
    #pragma unroll
    for (int o=1;o<16;o<<=1) smv += __shfl_xor(smv, o);
    float rs = 1.f/smv;
    long trow = tw + 4*kg + q;
    P[trow*TS + r15]      = f2b(e0*rs);
    P[trow*TS + 16 + r15] = f2b(e1*rs);
  }
}

// ---- big MFMA GEMM: C[32768,1024] = A @ W^T  (A bf16 [M][K], W bf16 [N][K]) ----
// 256x256 tile, 512 threads (8 waves 2x4), BK=32, 4-slot LDS ring (128KB),
// 2-phase schedule w/ counted vmcnt, XOR-swizzled LDS reads.
// SIG=true fuses the read-attention epilogue: read = P @ rvT (one MFMA per
// fragment, K=32 slots), y = x + sigmoid(h+b)*read, written bf16.
template<bool SIG>
__global__ __launch_bounds__(512, 2) void k_gemm(const u16* __restrict__ A, const u16* __restrict__ Bw,
                                                 const float* __restrict__ bias, void* __restrict__ Cp,
                                                 const u16* __restrict__ P, const u16* __restrict__ rvT){
  __shared__ __align__(16) char sL[131072];
  int tid = threadIdx.x, lane = tid & 63, wv = tid >> 6;
  int bid = blockIdx.x;
  int wg = ((bid & 7) << 6) | (bid >> 3);   // XCD swizzle, 512 % 8 == 0 -> bijective
  int nt = wg & 3, mt = wg >> 2;
  int m0 = mt*256, n0 = nt*256;
  int wr = wv >> 2, wc = wv & 3;            // wave -> (m-half, n-quarter)
  int r15 = lane & 15, kg = lane >> 4;

  // LDS read byte-offsets (swizzled), constant over K-loop
  int ard[8], brd[4];
  #pragma unroll
  for (int i=0;i<8;i++){ int row = wr*128 + i*16 + r15; ard[i] = (row*64 + kg*16) ^ ((row&7)<<4); }
  #pragma unroll
  for (int j=0;j<4;j++){ int row = wc*64  + j*16 + r15; brd[j] = (row*64 + kg*16) ^ ((row&7)<<4); }

  // stage: linear LDS dest (gll16 = uniform base + lane*16); pre-inverse-swizzled global source.
  const u16* asrc[2]; const u16* bsrc[2]; int ldst[2];
  #pragma unroll
  for (int r=0;r<2;r++){
    int S  = (r*8 + wv)*64 + lane;
    int r1 = (S>>3)&1, r2 = (S>>4)&1;
    int r0 = ((S>>2)&1) ^ r2;
    int row = ((S>>3)<<1) | r0;
    int kh  = (S&3) ^ ((r1<<1) | r0);
    asrc[r] = A  + (size_t)(m0 + row)*TD + kh*8;
    bsrc[r] = Bw + (size_t)(n0 + row)*TD + kh*8;
    ldst[r] = (r*8 + wv)*1024;
  }

  f32x4 acc[8][4];
  #pragma unroll
  for (int i=0;i<8;i++){
    #pragma unroll
    for (int j=0;j<4;j++){ f32x4 z = {0,0,0,0}; acc[i][j] = z; }
  }

  auto stageA = [&](int t){
    char* slot = sL + (size_t)(t&3)*32768;
    int k0 = t*32;
    gll16(asrc[0] + k0, slot + ldst[0]);
    gll16(asrc[1] + k0, slot + ldst[1]);
  };
  auto stageB = [&](int t){
    char* slot = sL + (size_t)(t&3)*32768;
    int k0 = t*32;
    gll16(bsrc[0] + k0, slot + 16384 + ldst[0]);
    gll16(bsrc[1] + k0, slot + 16384 + ldst[1]);
  };

  auto tile = [&](int t, bool prefetch){
    const char* sa = sL + (size_t)(t&3)*32768;
    const char* sb = sa + 16384;
    // phase 0
    bf16x8 bfg[4], af[4];
    #pragma unroll
    for (int j=0;j<4;j++) bfg[j] = *(const bf16x8*)(sb + brd[j]);
    #pragma unroll
    for (int i=0;i<4;i++) af[i] = *(const bf16x8*)(sa + ard[i]);
    if (prefetch) stageA(t+3);
    __builtin_amdgcn_s_barrier();
    LGKM0();
    __builtin_amdgcn_sched_barrier(0);
    __builtin_amdgcn_s_setprio(1);
    #pragma unroll
    for (int i=0;i<4;i++){
      #pragma unroll
      for (int j=0;j<4;j++)
        acc[i][j] = __builtin_amdgcn_mfma_f32_16x16x32_bf16(af[i], bfg[j], acc[i][j], 0,0,0);
    }
    __builtin_amdgcn_s_setprio(0);
    // phase 1
    bf16x8 af2[4];
    #pragma unroll
    for (int i=0;i<4;i++) af2[i] = *(const bf16x8*)(sa + ard[4+i]);
    if (prefetch) stageB(t+3);
    __builtin_amdgcn_s_barrier();
    LGKM0();
    __builtin_amdgcn_sched_barrier(0);
    __builtin_amdgcn_s_setprio(1);
    #pragma unroll
    for (int i=0;i<4;i++){
      #pragma unroll
      for (int j=0;j<4;j++)
        acc[4+i][j] = __builtin_amdgcn_mfma_f32_16x16x32_bf16(af2[i], bfg[j], acc[4+i][j], 0,0,0);
    }
    __builtin_amdgcn_s_setprio(0);
  };

  stageA(0); stageB(0); stageA(1); stageB(1); stageA(2); stageB(2);

  for (int t=0; t<30; ++t){
    VMWAIT(8);
    __builtin_amdgcn_s_barrier();
    tile(t, t < 29);
  }
  VMWAIT(4); __builtin_amdgcn_s_barrier(); tile(30, false);
  VMWAIT(0); __builtin_amdgcn_s_barrier(); tile(31, false);

  // epilogue: C row = kg*4+q, col = r15
  if (SIG){
    int b = m0 >> 13;
    // rvT B-frags: col rows, k = slot
    bf16x8 vfrag[4];
    #pragma unroll
    for (int j=0;j<4;j++){
      int n = n0 + wc*64 + j*16 + r15;
      vfrag[j] = *(const bf16x8*)(rvT + ((size_t)b*TD + n)*TS + kg*8);
    }
    #pragma unroll
    for (int i=0;i<8;i++){
      int tokbase = m0 + wr*128 + i*16;
      bf16x8 pfrag = *(const bf16x8*)(P + (size_t)(tokbase + r15)*TS + kg*8);
      f32x4 rd[4];
      #pragma unroll
      for (int j=0;j<4;j++){
        f32x4 z = {0,0,0,0};
        rd[j] = __builtin_amdgcn_mfma_f32_16x16x32_bf16(pfrag, vfrag[j], z, 0,0,0);
      }
      int mrow = tokbase + kg*4;
      #pragma unroll
      for (int j=0;j<4;j++){
        int n = n0 + wc*64 + j*16 + r15;
        float bj = bias[n];
        #pragma unroll
        for (int q=0;q<4;q++){
          float g = 1.f/(1.f + __expf(-(acc[i][j][q] + bj)));
          size_t idx = (size_t)(mrow + q)*TD + n;
          float xv = b2f(A[idx]);   // A == xb
          ((u16*)Cp)[idx] = f2b(xv + g*rd[j][q]);
        }
      }
    }
  } else {
    #pragma unroll
    for (int i=0;i<8;i++){
      int mrow = m0 + wr*128 + i*16 + kg*4;
      #pragma unroll
      for (int j=0;j<4;j++){
        int n = n0 + wc*64 + j*16 + r15;
        #pragma unroll
        for (int q=0;q<4;q++){
          size_t idx = (size_t)(mrow + q)*TD + n;
          ((float*)Cp)[idx] = acc[i][j][q];
        }
      }
    }
  }
}

extern "C" void kernel_launch(void* const* d_in, const int* in_sizes, int n_in,
                              void* d_out, int out_size, void* d_ws, size_t ws_size,
                              hipStream_t stream){
  const float* x   = (const float*)d_in[0];
  const float* gw  = (const float*)d_in[1];
  const float* gb  = (const float*)d_in[2];
  const float* rqw = (const float*)d_in[3];
  const float* rkw = (const float*)d_in[4];
  const float* rvw = (const float*)d_in[5];
  const float* ow  = (const float*)d_in[6];
  const float* ms  = (const float*)d_in[7];
  const float* wqw = (const float*)d_in[8];
  const float* wkw = (const float*)d_in[9];
  const float* wvw = (const float*)d_in[10];
  float* out = (float*)d_out;
  float* mem_out = out + (size_t)BT*TD;

  // xb (bf16 copy of x, 64MB) lives in the front 64MB of d_out; P (2MB) in
  // the second 64MB. Both dead before the final GEMM overwrites d_out.
  u16* xb = (u16*)d_out;
  u16* Pb = (u16*)((char*)d_out + 67108864);

  char* w = (char*)d_ws;
  u16*   gy    = (u16*)(w);                    // 64MB  (y = x + g*read)
  float* wqkb  = (float*)(w + 67108864);       // 128KB
  float* qb    = (float*)(w + 67239936);       // 128KB
  float* qkb   = (float*)(w + 67371008);       // 128KB
  float* xbarb = (float*)(w + 67502080);       // 512KB
  float* memb  = (float*)(w + 68026368);       // 512KB
  float* rkbf  = (float*)(w + 68550656);       // 512KB
  u16*   rkb   = (u16*)(w + 69074944);         // 256KB
  u16*   rvT   = (u16*)(w + 69337088);         // 256KB
  u16*   gwb   = (u16*)(w + 69599232);         // 2MB
  u16*   owb   = (u16*)(w + 71696384);         // 2MB

  k_convw2<<<2048,256,0,stream>>>(gw, ow, gwb, owb);
  k_prep_q<<<dim3(4,32),256,0,stream>>>(ms, wqw, qb);
  k_prep_qk<<<dim3(32,4),256,0,stream>>>(qb, wkw, qkb);
  k_conv_dot<<<2048,256,0,stream>>>(x, qkb, xb, wqkb);
  k_wattn<<<dim3(128,4),256,0,stream>>>(wqkb, xb, xbarb);
  // memory = xbar @ Wv^T   (also written to output slot 1)
  k_mm<<<dim3(64,4),256,0,stream>>>(xbarb, wvw, 1, 1.f, memb, mem_out, nullptr, nullptr);
  // rk = memory @ Wrk^T ; rv = memory @ Wrv^T -> transposed bf16 [b][d][s]
  k_mm23<<<dim3(64,4,2),256,0,stream>>>(memb, rkw, rvw, rkbf, rvT);
  // rk~ = scale * rk @ Wrq -> bf16 [b*s][d]
  k_mm<<<dim3(64,4),256,0,stream>>>(rkbf, rqw, 0, 1.f/32.f, nullptr, nullptr, rkb, nullptr);
  // P = softmax(mask(xb @ rk~^T)) normalized, bf16 [BT][32]
  k_pattn<<<512,256,0,stream>>>(xb, rkb, Pb);
  // y = x + sigmoid(x@gate_w^T + gb) * (P @ rvT)   [fused]
  k_gemm<true><<<512,512,0,stream>>>(xb, gwb, gb, gy, Pb, rvT);
  // out = y @ output_w^T
  k_gemm<false><<<512,512,0,stream>>>(gy, owb, nullptr, d_out, nullptr, nullptr);
}